// Round 1
// baseline (1436.570 us; speedup 1.0000x reference)
//
#include <hip/hip_runtime.h>
#include <math.h>

#define TPB 256
#define ENC_NEG_INF 0x007FFFFFu

static __device__ __forceinline__ float lrelu(float x) { return x > 0.f ? x : 0.2f * x; }

// monotone float->uint encoding so unsigned atomicMax == float max
static __device__ __forceinline__ void atomicMaxF(unsigned int* addr, float v) {
  unsigned int u = __float_as_uint(v);
  u = (u & 0x80000000u) ? ~u : (u | 0x80000000u);
  atomicMax(addr, u);
}
static __device__ __forceinline__ float decodeMaxU(unsigned int u) {
  unsigned int bits = (u & 0x80000000u) ? (u & 0x7fffffffu) : ~u;
  return __uint_as_float(bits);
}

// ---------------- CSR build (graph is identical for all 3 layers) -------------
__global__ void k_hist(const int* __restrict__ dstE, int E, int N, int* __restrict__ deg) {
  int e = blockIdx.x * TPB + threadIdx.x;
  if (e >= E + N) return;
  int d = (e < E) ? dstE[e] : (e - E);
  d = min(max(d, 0), N - 1);
  atomicAdd(&deg[d], 1);
}

__global__ void k_scan1(const int* __restrict__ deg, int N, int* __restrict__ csum) {
  __shared__ int sm[TPB];
  int t = threadIdx.x, i = blockIdx.x * TPB + t;
  sm[t] = (i < N) ? deg[i] : 0;
  __syncthreads();
  for (int off = TPB / 2; off; off >>= 1) {
    if (t < off) sm[t] += sm[t + off];
    __syncthreads();
  }
  if (t == 0) csum[blockIdx.x] = sm[0];
}

__global__ void k_scan2(int* __restrict__ csum, int nch) {
  __shared__ int sm[TPB];
  int t = threadIdx.x;
  int v = (t < nch) ? csum[t] : 0;
  sm[t] = v;
  __syncthreads();
  for (int off = 1; off < TPB; off <<= 1) {
    int add = (t >= off) ? sm[t - off] : 0;
    __syncthreads();
    sm[t] += add;
    __syncthreads();
  }
  if (t < nch) csum[t] = (t == 0) ? 0 : sm[t - 1];  // exclusive chunk offsets
}

__global__ void k_scan3(const int* __restrict__ deg, const int* __restrict__ csum, int N, int total,
                        int* __restrict__ row_ptr, int* __restrict__ cursor) {
  __shared__ int sm[TPB];
  int b = blockIdx.x, t = threadIdx.x, i = b * TPB + t;
  int v = (i < N) ? deg[i] : 0;
  sm[t] = v;
  __syncthreads();
  for (int off = 1; off < TPB; off <<= 1) {
    int add = (t >= off) ? sm[t - off] : 0;
    __syncthreads();
    sm[t] += add;
    __syncthreads();
  }
  if (i < N) {
    int rp = csum[b] + sm[t] - v;  // exclusive
    row_ptr[i] = rp;
    cursor[i] = rp;
  }
  if (i == 0) row_ptr[N] = total;
}

__global__ void k_scatter(const int* __restrict__ srcE, const int* __restrict__ dstE, int E, int N,
                          int* __restrict__ cursor, int* __restrict__ csr_src, int* __restrict__ csr_eid) {
  int e = blockIdx.x * TPB + threadIdx.x;
  if (e >= E + N) return;
  int s = (e < E) ? srcE[e] : (e - E);
  int d = (e < E) ? dstE[e] : (e - E);
  s = min(max(s, 0), N - 1);
  d = min(max(d, 0), N - 1);
  int pos = atomicAdd(&cursor[d], 1);
  csr_src[pos] = s;
  csr_eid[pos] = e;
}

// ---------------- GEMM: H = X @ cW (128x128), S = X @ sW^T (sW is 128x128) ----
// combined weight WB[k][j]: j<128 -> cW[k][j], j>=128 -> sW[j-128][k]
__global__ void k_prep_w(const float* __restrict__ cW, const float* __restrict__ sW, float* __restrict__ WB) {
  int k = blockIdx.x;   // 0..127
  int j = threadIdx.x;  // 0..255
  WB[k * 256 + j] = (j < 128) ? cW[k * 128 + j] : sW[(j - 128) * 128 + k];
}

__global__ __launch_bounds__(TPB) void k_gemm(const float* __restrict__ X, const float* __restrict__ WB,
                                              float* __restrict__ Hb, float* __restrict__ Sb, int N) {
  __shared__ float Xs[32][128];
  int r0 = blockIdx.x * 32;
  int tid = threadIdx.x;
  int nrow = min(32, N - r0);
  const float4* Xv = (const float4*)(X + (size_t)r0 * 128);
  float4* Xsv = (float4*)(&Xs[0][0]);
  for (int i = tid; i < nrow * 32; i += TPB) Xsv[i] = Xv[i];
  __syncthreads();

  float acc[32];
#pragma unroll
  for (int r = 0; r < 32; ++r) acc[r] = 0.f;

  const float* wp = WB + tid;
#pragma unroll 1
  for (int k4 = 0; k4 < 32; ++k4) {
    float w0 = wp[(k4 * 4 + 0) * 256];
    float w1 = wp[(k4 * 4 + 1) * 256];
    float w2 = wp[(k4 * 4 + 2) * 256];
    float w3 = wp[(k4 * 4 + 3) * 256];
#pragma unroll
    for (int r = 0; r < 32; ++r) {
      float4 xv = *(const float4*)(&Xs[r][k4 * 4]);
      acc[r] = fmaf(xv.x, w0, acc[r]);
      acc[r] = fmaf(xv.y, w1, acc[r]);
      acc[r] = fmaf(xv.z, w2, acc[r]);
      acc[r] = fmaf(xv.w, w3, acc[r]);
    }
  }
  float* outp = (tid < 128) ? (Hb + (size_t)r0 * 128 + tid) : (Sb + (size_t)r0 * 128 + (tid - 128));
  for (int r = 0; r < nrow; ++r) outp[(size_t)r * 128] = acc[r];
}

// ---------------- per-node attention coefficients a_s, a_d -------------------
__global__ void k_asad(const float* __restrict__ Hh, const float* __restrict__ asrc, const float* __restrict__ adst,
                       float* __restrict__ a_s, float* __restrict__ a_d, int N) {
  int i = blockIdx.x * TPB + threadIdx.x;
  if (i >= N * 4) return;
  int n = i >> 2, h = i & 3;
  const float* hp = Hh + (size_t)n * 128 + h * 32;
  const float* ap = asrc + h * 32;
  const float* bp = adst + h * 32;
  float sa = 0.f, sd = 0.f;
#pragma unroll
  for (int c = 0; c < 32; c += 4) {
    float4 hv = *(const float4*)(hp + c);
    float4 av = *(const float4*)(ap + c);
    float4 dv = *(const float4*)(bp + c);
    sa += hv.x * av.x + hv.y * av.y + hv.z * av.z + hv.w * av.w;
    sd += hv.x * dv.x + hv.y * dv.y + hv.z * dv.z + hv.w * dv.w;
  }
  a_s[i] = sa;
  a_d[i] = sd;
}

__global__ void k_init_ms(unsigned int* __restrict__ m, float* __restrict__ s, int count) {
  int i = blockIdx.x * TPB + threadIdx.x;
  if (i >= count) return;
  m[i] = ENC_NEG_INF;
  s[i] = 0.f;
}

// ---------------- edge passes (H=4) ------------------------------------------
__global__ void k_edge_logits(const int* __restrict__ srcE, const int* __restrict__ dstE, int E, int N,
                              const float* __restrict__ a_s, const float* __restrict__ a_d,
                              float4* __restrict__ e_buf, unsigned int* __restrict__ m) {
  int e = blockIdx.x * TPB + threadIdx.x;
  if (e >= E + N) return;
  int s = (e < E) ? srcE[e] : (e - E);
  int d = (e < E) ? dstE[e] : (e - E);
  s = min(max(s, 0), N - 1);
  d = min(max(d, 0), N - 1);
  float4 as = ((const float4*)a_s)[s];
  float4 ad = ((const float4*)a_d)[d];
  float4 lg;
  lg.x = lrelu(as.x + ad.x);
  lg.y = lrelu(as.y + ad.y);
  lg.z = lrelu(as.z + ad.z);
  lg.w = lrelu(as.w + ad.w);
  e_buf[e] = lg;
  atomicMaxF(&m[d * 4 + 0], lg.x);
  atomicMaxF(&m[d * 4 + 1], lg.y);
  atomicMaxF(&m[d * 4 + 2], lg.z);
  atomicMaxF(&m[d * 4 + 3], lg.w);
}

__global__ void k_edge_exp(const int* __restrict__ dstE, int E, int N, float4* __restrict__ e_buf,
                           const unsigned int* __restrict__ m, float* __restrict__ ssum) {
  int e = blockIdx.x * TPB + threadIdx.x;
  if (e >= E + N) return;
  int d = (e < E) ? dstE[e] : (e - E);
  d = min(max(d, 0), N - 1);
  float4 lg = e_buf[e];
  float4 p;
  p.x = __expf(lg.x - decodeMaxU(m[d * 4 + 0]));
  p.y = __expf(lg.y - decodeMaxU(m[d * 4 + 1]));
  p.z = __expf(lg.z - decodeMaxU(m[d * 4 + 2]));
  p.w = __expf(lg.w - decodeMaxU(m[d * 4 + 3]));
  e_buf[e] = p;
  atomicAdd(&ssum[d * 4 + 0], p.x);
  atomicAdd(&ssum[d * 4 + 1], p.y);
  atomicAdd(&ssum[d * 4 + 2], p.z);
  atomicAdd(&ssum[d * 4 + 3], p.w);
}

// gather-aggregate per dst node + bias + skip + relu (writes next layer input)
__global__ __launch_bounds__(TPB) void k_aggregate(const int* __restrict__ row_ptr, const int* __restrict__ csr_src,
                                                   const int* __restrict__ csr_eid, const float* __restrict__ Hh,
                                                   const float* __restrict__ e_buf, const float* __restrict__ ssum,
                                                   const float* __restrict__ Sk, const float* __restrict__ cb,
                                                   const float* __restrict__ sb, float* __restrict__ Xn, int N) {
  int n = blockIdx.x * 2 + (threadIdx.x >> 7);
  int c = threadIdx.x & 127;
  if (n >= N) return;
  int h = c >> 5;
  int beg = row_ptr[n], end = row_ptr[n + 1];
  float inv = 1.f / (ssum[n * 4 + h] + 1e-16f);
  float acc = 0.f;
  for (int p = beg; p < end; ++p) {
    int s = csr_src[p];
    int eid = csr_eid[p];
    float al = e_buf[(size_t)eid * 4 + h];
    acc = fmaf(al, Hh[(size_t)s * 128 + c], acc);
  }
  float v = acc * inv + cb[c] + Sk[(size_t)n * 128 + c] + sb[c];
  Xn[(size_t)n * 128 + c] = fmaxf(v, 0.f);
}

// ---------------- layer 2 (H=1, C=1) -----------------------------------------
__global__ void k_l2_lin(const float* __restrict__ X, const float* __restrict__ c2w, const float* __restrict__ s2w,
                         const float* __restrict__ c2as, const float* __restrict__ c2ad, float* __restrict__ h2,
                         float* __restrict__ sk2, float* __restrict__ as2, float* __restrict__ ad2, int N) {
  int gid = blockIdx.x * TPB + threadIdx.x;
  int n = gid >> 6;
  int lane = threadIdx.x & 63;
  if (n >= N) return;
  const float* xp = X + (size_t)n * 128;
  float2 xv = *(const float2*)(xp + lane * 2);
  float2 wv = *(const float2*)(c2w + lane * 2);
  float2 sv = *(const float2*)(s2w + lane * 2);
  float dh = xv.x * wv.x + xv.y * wv.y;
  float ds = xv.x * sv.x + xv.y * sv.y;
  for (int off = 32; off; off >>= 1) {
    dh += __shfl_down(dh, off);
    ds += __shfl_down(ds, off);
  }
  if (lane == 0) {
    h2[n] = dh;
    sk2[n] = ds;
    as2[n] = dh * c2as[0];
    ad2[n] = dh * c2ad[0];
  }
}

__global__ void k_l2_logits(const int* __restrict__ srcE, const int* __restrict__ dstE, int E, int N,
                            const float* __restrict__ as2, const float* __restrict__ ad2, float* __restrict__ e2,
                            unsigned int* __restrict__ m2) {
  int e = blockIdx.x * TPB + threadIdx.x;
  if (e >= E + N) return;
  int s = (e < E) ? srcE[e] : (e - E);
  int d = (e < E) ? dstE[e] : (e - E);
  s = min(max(s, 0), N - 1);
  d = min(max(d, 0), N - 1);
  float x = lrelu(as2[s] + ad2[d]);
  e2[e] = x;
  atomicMaxF(&m2[d], x);
}

__global__ void k_l2_exp(const int* __restrict__ dstE, int E, int N, float* __restrict__ e2,
                         const unsigned int* __restrict__ m2, float* __restrict__ s2) {
  int e = blockIdx.x * TPB + threadIdx.x;
  if (e >= E + N) return;
  int d = (e < E) ? dstE[e] : (e - E);
  d = min(max(d, 0), N - 1);
  float p = __expf(e2[e] - decodeMaxU(m2[d]));
  e2[e] = p;
  atomicAdd(&s2[d], p);
}

__global__ void k_l2_agg(const int* __restrict__ row_ptr, const int* __restrict__ csr_src,
                         const int* __restrict__ csr_eid, const float* __restrict__ h2, const float* __restrict__ e2,
                         const float* __restrict__ s2, const float* __restrict__ sk2, const float* __restrict__ c2b,
                         const float* __restrict__ s2b, float* __restrict__ out, int N) {
  int n = blockIdx.x * TPB + threadIdx.x;
  if (n >= N) return;
  int beg = row_ptr[n], end = row_ptr[n + 1];
  float acc = 0.f;
  for (int p = beg; p < end; ++p) acc += e2[csr_eid[p]] * h2[csr_src[p]];
  float v = acc / (s2[n] + 1e-16f) + c2b[0] + sk2[n] + s2b[0];
  out[n] = 1.f / (1.f + __expf(-v));
}

// ---------------- host orchestration -----------------------------------------
extern "C" void kernel_launch(void* const* d_in, const int* in_sizes, int n_in,
                              void* d_out, int out_size, void* d_ws, size_t ws_size,
                              hipStream_t stream) {
  const float* x = (const float*)d_in[0];
  const int* ei = (const int*)d_in[1];
  const float* c0_w = (const float*)d_in[3];
  const float* c0_as = (const float*)d_in[4];
  const float* c0_ad = (const float*)d_in[5];
  const float* c0_b = (const float*)d_in[6];
  const float* s0_w = (const float*)d_in[7];
  const float* s0_b = (const float*)d_in[8];
  const float* c1_w = (const float*)d_in[9];
  const float* c1_as = (const float*)d_in[10];
  const float* c1_ad = (const float*)d_in[11];
  const float* c1_b = (const float*)d_in[12];
  const float* s1_w = (const float*)d_in[13];
  const float* s1_b = (const float*)d_in[14];
  const float* c2_w = (const float*)d_in[15];
  const float* c2_as = (const float*)d_in[16];
  const float* c2_ad = (const float*)d_in[17];
  const float* c2_b = (const float*)d_in[18];
  const float* s2_w = (const float*)d_in[19];
  const float* s2_b = (const float*)d_in[20];

  const int N = in_sizes[0] / 128;
  const int E = in_sizes[1] / 2;
  const int EN = E + N;
  const int* srcE = ei;
  const int* dstE = ei + E;

  // bump allocator over d_ws
  char* wp_ = (char*)d_ws;
  auto alloc = [&](size_t bytes) -> void* {
    void* r = (void*)wp_;
    wp_ += (bytes + 255) & ~(size_t)255;
    return r;
  };
  float* P0 = (float*)alloc((size_t)N * 128 * 4);  // H (lin out)
  float* P1 = (float*)alloc((size_t)N * 128 * 4);  // skip
  float* P2 = (float*)alloc((size_t)N * 128 * 4);  // layer outputs (in-place rotate)
  float* a_s = (float*)alloc((size_t)N * 4 * 4);
  float* a_d = (float*)alloc((size_t)N * 4 * 4);
  unsigned int* mbuf = (unsigned int*)alloc((size_t)N * 4 * 4);
  float* ssum = (float*)alloc((size_t)N * 4 * 4);
  float* e_buf = (float*)alloc((size_t)EN * 4 * 4);
  float* WB = (float*)alloc(128 * 256 * 4);
  int* deg = (int*)alloc((size_t)N * 4);
  int* row_ptr = (int*)alloc((size_t)(N + 1) * 4);
  int* cursor = (int*)alloc((size_t)N * 4);
  int* csum = (int*)alloc(4096 * 4);
  int* csr_src = (int*)alloc((size_t)EN * 4);
  int* csr_eid = (int*)alloc((size_t)EN * 4);
  float* h2 = (float*)alloc((size_t)N * 4);
  float* sk2 = (float*)alloc((size_t)N * 4);
  float* as2 = (float*)alloc((size_t)N * 4);
  float* ad2 = (float*)alloc((size_t)N * 4);

  const int gEN = (EN + TPB - 1) / TPB;
  const int gN4 = (N * 4 + TPB - 1) / TPB;
  const int gN = (N + TPB - 1) / TPB;
  const int nch = (N + TPB - 1) / TPB;
  const int gGemm = (N + 31) / 32;

  // ---- CSR build (once per call; graph shared by all layers) ----
  hipMemsetAsync(deg, 0, (size_t)N * 4, stream);
  k_hist<<<gEN, TPB, 0, stream>>>(dstE, E, N, deg);
  k_scan1<<<nch, TPB, 0, stream>>>(deg, N, csum);
  k_scan2<<<1, TPB, 0, stream>>>(csum, nch);
  k_scan3<<<nch, TPB, 0, stream>>>(deg, csum, N, EN, row_ptr, cursor);
  k_scatter<<<gEN, TPB, 0, stream>>>(srcE, dstE, E, N, cursor, csr_src, csr_eid);

  // ---- layer 0 ----
  k_prep_w<<<128, TPB, 0, stream>>>(c0_w, s0_w, WB);
  k_gemm<<<gGemm, TPB, 0, stream>>>(x, WB, P0, P1, N);
  k_asad<<<gN4, TPB, 0, stream>>>(P0, c0_as, c0_ad, a_s, a_d, N);
  k_init_ms<<<gN4, TPB, 0, stream>>>(mbuf, ssum, N * 4);
  k_edge_logits<<<gEN, TPB, 0, stream>>>(srcE, dstE, E, N, a_s, a_d, (float4*)e_buf, mbuf);
  k_edge_exp<<<gEN, TPB, 0, stream>>>(dstE, E, N, (float4*)e_buf, mbuf, ssum);
  k_aggregate<<<(N + 1) / 2, TPB, 0, stream>>>(row_ptr, csr_src, csr_eid, P0, e_buf, ssum, P1, c0_b, s0_b, P2, N);

  // ---- layer 1 (input P2, output overwrites P2) ----
  k_prep_w<<<128, TPB, 0, stream>>>(c1_w, s1_w, WB);
  k_gemm<<<gGemm, TPB, 0, stream>>>(P2, WB, P0, P1, N);
  k_asad<<<gN4, TPB, 0, stream>>>(P0, c1_as, c1_ad, a_s, a_d, N);
  k_init_ms<<<gN4, TPB, 0, stream>>>(mbuf, ssum, N * 4);
  k_edge_logits<<<gEN, TPB, 0, stream>>>(srcE, dstE, E, N, a_s, a_d, (float4*)e_buf, mbuf);
  k_edge_exp<<<gEN, TPB, 0, stream>>>(dstE, E, N, (float4*)e_buf, mbuf, ssum);
  k_aggregate<<<(N + 1) / 2, TPB, 0, stream>>>(row_ptr, csr_src, csr_eid, P0, e_buf, ssum, P1, c1_b, s1_b, P2, N);

  // ---- layer 2 (H=1,C=1) ----
  k_l2_lin<<<(N * 64 + TPB - 1) / TPB, TPB, 0, stream>>>(P2, c2_w, s2_w, c2_as, c2_ad, h2, sk2, as2, ad2, N);
  k_init_ms<<<gN, TPB, 0, stream>>>(mbuf, ssum, N);
  k_l2_logits<<<gEN, TPB, 0, stream>>>(srcE, dstE, E, N, as2, ad2, e_buf, mbuf);
  k_l2_exp<<<gEN, TPB, 0, stream>>>(dstE, E, N, e_buf, mbuf, ssum);
  k_l2_agg<<<gN, TPB, 0, stream>>>(row_ptr, csr_src, csr_eid, h2, e_buf, ssum, sk2, c2_b, s2_b, (float*)d_out, N);
}

// Round 2
// 785.858 us; speedup vs baseline: 1.8280x; 1.8280x over previous
//
#include <hip/hip_runtime.h>
#include <math.h>

#define TPB 256

static __device__ __forceinline__ float lrelu(float x) { return x > 0.f ? x : 0.2f * x; }

// ---------------- CSR build (graph is identical for all 3 layers) -------------
__global__ void k_hist(const int* __restrict__ dstE, int E, int N, int* __restrict__ deg) {
  int e = blockIdx.x * TPB + threadIdx.x;
  if (e >= E + N) return;
  int d = (e < E) ? dstE[e] : (e - E);
  d = min(max(d, 0), N - 1);
  atomicAdd(&deg[d], 1);
}

__global__ void k_scan1(const int* __restrict__ deg, int N, int* __restrict__ csum) {
  __shared__ int sm[TPB];
  int t = threadIdx.x, i = blockIdx.x * TPB + t;
  sm[t] = (i < N) ? deg[i] : 0;
  __syncthreads();
  for (int off = TPB / 2; off; off >>= 1) {
    if (t < off) sm[t] += sm[t + off];
    __syncthreads();
  }
  if (t == 0) csum[blockIdx.x] = sm[0];
}

__global__ void k_scan2(int* __restrict__ csum, int nch) {
  __shared__ int sm[TPB];
  int t = threadIdx.x;
  int v = (t < nch) ? csum[t] : 0;
  sm[t] = v;
  __syncthreads();
  for (int off = 1; off < TPB; off <<= 1) {
    int add = (t >= off) ? sm[t - off] : 0;
    __syncthreads();
    sm[t] += add;
    __syncthreads();
  }
  if (t < nch) csum[t] = (t == 0) ? 0 : sm[t - 1];  // exclusive chunk offsets
}

__global__ void k_scan3(const int* __restrict__ deg, const int* __restrict__ csum, int N, int total,
                        int* __restrict__ row_ptr, int* __restrict__ cursor) {
  __shared__ int sm[TPB];
  int b = blockIdx.x, t = threadIdx.x, i = b * TPB + t;
  int v = (i < N) ? deg[i] : 0;
  sm[t] = v;
  __syncthreads();
  for (int off = 1; off < TPB; off <<= 1) {
    int add = (t >= off) ? sm[t - off] : 0;
    __syncthreads();
    sm[t] += add;
    __syncthreads();
  }
  if (i < N) {
    int rp = csum[b] + sm[t] - v;  // exclusive
    row_ptr[i] = rp;
    cursor[i] = rp;
  }
  if (i == 0) row_ptr[N] = total;
}

__global__ void k_scatter(const int* __restrict__ srcE, const int* __restrict__ dstE, int E, int N,
                          int* __restrict__ cursor, int* __restrict__ csr_src) {
  int e = blockIdx.x * TPB + threadIdx.x;
  if (e >= E + N) return;
  int s = (e < E) ? srcE[e] : (e - E);
  int d = (e < E) ? dstE[e] : (e - E);
  s = min(max(s, 0), N - 1);
  d = min(max(d, 0), N - 1);
  int pos = atomicAdd(&cursor[d], 1);
  csr_src[pos] = s;
}

// ---------------- GEMM: H = X @ cW (128x128), S = X @ sW^T (sW is 128x128) ----
__global__ void k_prep_w(const float* __restrict__ cW, const float* __restrict__ sW, float* __restrict__ WB) {
  int k = blockIdx.x;   // 0..127
  int j = threadIdx.x;  // 0..255
  WB[k * 256 + j] = (j < 128) ? cW[k * 128 + j] : sW[(j - 128) * 128 + k];
}

__global__ __launch_bounds__(TPB) void k_gemm(const float* __restrict__ X, const float* __restrict__ WB,
                                              float* __restrict__ Hb, float* __restrict__ Sb, int N) {
  __shared__ float Xs[32][128];
  int r0 = blockIdx.x * 32;
  int tid = threadIdx.x;
  int nrow = min(32, N - r0);
  const float4* Xv = (const float4*)(X + (size_t)r0 * 128);
  float4* Xsv = (float4*)(&Xs[0][0]);
  for (int i = tid; i < nrow * 32; i += TPB) Xsv[i] = Xv[i];
  __syncthreads();

  float acc[32];
#pragma unroll
  for (int r = 0; r < 32; ++r) acc[r] = 0.f;

  const float* wp = WB + tid;
#pragma unroll 1
  for (int k4 = 0; k4 < 32; ++k4) {
    float w0 = wp[(k4 * 4 + 0) * 256];
    float w1 = wp[(k4 * 4 + 1) * 256];
    float w2 = wp[(k4 * 4 + 2) * 256];
    float w3 = wp[(k4 * 4 + 3) * 256];
#pragma unroll
    for (int r = 0; r < 32; ++r) {
      float4 xv = *(const float4*)(&Xs[r][k4 * 4]);
      acc[r] = fmaf(xv.x, w0, acc[r]);
      acc[r] = fmaf(xv.y, w1, acc[r]);
      acc[r] = fmaf(xv.z, w2, acc[r]);
      acc[r] = fmaf(xv.w, w3, acc[r]);
    }
  }
  float* outp = (tid < 128) ? (Hb + (size_t)r0 * 128 + tid) : (Sb + (size_t)r0 * 128 + (tid - 128));
  for (int r = 0; r < nrow; ++r) outp[(size_t)r * 128] = acc[r];
}

// ---------------- per-node attention coefficients a_s, a_d -------------------
__global__ void k_asad(const float* __restrict__ Hh, const float* __restrict__ asrc, const float* __restrict__ adst,
                       float* __restrict__ a_s, float* __restrict__ a_d, int N) {
  int i = blockIdx.x * TPB + threadIdx.x;
  if (i >= N * 4) return;
  int n = i >> 2, h = i & 3;
  const float* hp = Hh + (size_t)n * 128 + h * 32;
  const float* ap = asrc + h * 32;
  const float* bp = adst + h * 32;
  float sa = 0.f, sd = 0.f;
#pragma unroll
  for (int c = 0; c < 32; c += 4) {
    float4 hv = *(const float4*)(hp + c);
    float4 av = *(const float4*)(ap + c);
    float4 dv = *(const float4*)(bp + c);
    sa += hv.x * av.x + hv.y * av.y + hv.z * av.z + hv.w * av.w;
    sd += hv.x * dv.x + hv.y * dv.y + hv.z * dv.z + hv.w * dv.w;
  }
  a_s[i] = sa;
  a_d[i] = sd;
}

// ---------------- CSR softmax, wave-per-node (H=4) ----------------------------
// Writes unnormalized alpha (CSR order) + per-node/head sums. Zero atomics.
__global__ __launch_bounds__(TPB) void k_softmax4(const int* __restrict__ row_ptr, const int* __restrict__ csr_src,
                                                  const float4* __restrict__ a_s4, const float4* __restrict__ a_d4,
                                                  float4* __restrict__ alpha, float* __restrict__ ssum, int N) {
  int n = blockIdx.x * 4 + (threadIdx.x >> 6);
  if (n >= N) return;
  int lane = threadIdx.x & 63;
  int beg = row_ptr[n], end = row_ptr[n + 1];
  int deg = end - beg;
  float4 ad = a_d4[n];

  float4 mx = make_float4(-1e30f, -1e30f, -1e30f, -1e30f);
  float4 lg0 = mx;
  if (deg <= 64) {
    if (lane < deg) {
      int s = csr_src[beg + lane];
      float4 as = a_s4[s];
      lg0.x = lrelu(as.x + ad.x);
      lg0.y = lrelu(as.y + ad.y);
      lg0.z = lrelu(as.z + ad.z);
      lg0.w = lrelu(as.w + ad.w);
      mx = lg0;
    }
  } else {
    for (int p = beg + lane; p < end; p += 64) {
      int s = csr_src[p];
      float4 as = a_s4[s];
      float4 lg;
      lg.x = lrelu(as.x + ad.x);
      lg.y = lrelu(as.y + ad.y);
      lg.z = lrelu(as.z + ad.z);
      lg.w = lrelu(as.w + ad.w);
      alpha[p] = lg;
      mx.x = fmaxf(mx.x, lg.x);
      mx.y = fmaxf(mx.y, lg.y);
      mx.z = fmaxf(mx.z, lg.z);
      mx.w = fmaxf(mx.w, lg.w);
    }
  }
#pragma unroll
  for (int off = 32; off; off >>= 1) {
    mx.x = fmaxf(mx.x, __shfl_xor(mx.x, off));
    mx.y = fmaxf(mx.y, __shfl_xor(mx.y, off));
    mx.z = fmaxf(mx.z, __shfl_xor(mx.z, off));
    mx.w = fmaxf(mx.w, __shfl_xor(mx.w, off));
  }

  float4 sm = make_float4(0.f, 0.f, 0.f, 0.f);
  if (deg <= 64) {
    if (lane < deg) {
      float4 pv;
      pv.x = __expf(lg0.x - mx.x);
      pv.y = __expf(lg0.y - mx.y);
      pv.z = __expf(lg0.z - mx.z);
      pv.w = __expf(lg0.w - mx.w);
      alpha[beg + lane] = pv;
      sm = pv;
    }
  } else {
    for (int p = beg + lane; p < end; p += 64) {
      float4 lg = alpha[p];
      float4 pv;
      pv.x = __expf(lg.x - mx.x);
      pv.y = __expf(lg.y - mx.y);
      pv.z = __expf(lg.z - mx.z);
      pv.w = __expf(lg.w - mx.w);
      alpha[p] = pv;
      sm.x += pv.x;
      sm.y += pv.y;
      sm.z += pv.z;
      sm.w += pv.w;
    }
  }
#pragma unroll
  for (int off = 32; off; off >>= 1) {
    sm.x += __shfl_xor(sm.x, off);
    sm.y += __shfl_xor(sm.y, off);
    sm.z += __shfl_xor(sm.z, off);
    sm.w += __shfl_xor(sm.w, off);
  }
  float sv = (lane == 0) ? sm.x : (lane == 1) ? sm.y : (lane == 2) ? sm.z : sm.w;
  if (lane < 4) ssum[n * 4 + lane] = sv;
}

// gather-aggregate per dst node + bias + skip + relu (writes next layer input)
__global__ __launch_bounds__(TPB) void k_aggregate(const int* __restrict__ row_ptr, const int* __restrict__ csr_src,
                                                   const float* __restrict__ Hh, const float* __restrict__ alpha,
                                                   const float* __restrict__ ssum, const float* __restrict__ Sk,
                                                   const float* __restrict__ cb, const float* __restrict__ sb,
                                                   float* __restrict__ Xn, int N) {
  int n = blockIdx.x * 2 + (threadIdx.x >> 7);
  int c = threadIdx.x & 127;
  if (n >= N) return;
  int h = c >> 5;
  int beg = row_ptr[n], end = row_ptr[n + 1];
  float inv = 1.f / (ssum[n * 4 + h] + 1e-16f);
  float acc = 0.f;
  for (int p = beg; p < end; ++p) {
    int s = csr_src[p];
    float al = alpha[(size_t)p * 4 + h];
    acc = fmaf(al, Hh[(size_t)s * 128 + c], acc);
  }
  float v = acc * inv + cb[c] + Sk[(size_t)n * 128 + c] + sb[c];
  Xn[(size_t)n * 128 + c] = fmaxf(v, 0.f);
}

// ---------------- layer 2 (H=1, C=1) -----------------------------------------
__global__ void k_l2_lin(const float* __restrict__ X, const float* __restrict__ c2w, const float* __restrict__ s2w,
                         const float* __restrict__ c2as, const float* __restrict__ c2ad, float* __restrict__ h2,
                         float* __restrict__ sk2, float* __restrict__ as2, float* __restrict__ ad2, int N) {
  int gid = blockIdx.x * TPB + threadIdx.x;
  int n = gid >> 6;
  int lane = threadIdx.x & 63;
  if (n >= N) return;
  const float* xp = X + (size_t)n * 128;
  float2 xv = *(const float2*)(xp + lane * 2);
  float2 wv = *(const float2*)(c2w + lane * 2);
  float2 sv = *(const float2*)(s2w + lane * 2);
  float dh = xv.x * wv.x + xv.y * wv.y;
  float ds = xv.x * sv.x + xv.y * sv.y;
  for (int off = 32; off; off >>= 1) {
    dh += __shfl_down(dh, off);
    ds += __shfl_down(ds, off);
  }
  if (lane == 0) {
    h2[n] = dh;
    sk2[n] = ds;
    as2[n] = dh * c2as[0];
    ad2[n] = dh * c2ad[0];
  }
}

// CSR softmax, wave-per-node (H=1)
__global__ __launch_bounds__(TPB) void k_l2_softmax(const int* __restrict__ row_ptr, const int* __restrict__ csr_src,
                                                    const float* __restrict__ as2, const float* __restrict__ ad2,
                                                    float* __restrict__ alpha, float* __restrict__ ssum, int N) {
  int n = blockIdx.x * 4 + (threadIdx.x >> 6);
  if (n >= N) return;
  int lane = threadIdx.x & 63;
  int beg = row_ptr[n], end = row_ptr[n + 1];
  int deg = end - beg;
  float ad = ad2[n];

  float mx = -1e30f, lg0 = -1e30f;
  if (deg <= 64) {
    if (lane < deg) {
      lg0 = lrelu(as2[csr_src[beg + lane]] + ad);
      mx = lg0;
    }
  } else {
    for (int p = beg + lane; p < end; p += 64) {
      float lg = lrelu(as2[csr_src[p]] + ad);
      alpha[p] = lg;
      mx = fmaxf(mx, lg);
    }
  }
#pragma unroll
  for (int off = 32; off; off >>= 1) mx = fmaxf(mx, __shfl_xor(mx, off));

  float sm = 0.f;
  if (deg <= 64) {
    if (lane < deg) {
      float pv = __expf(lg0 - mx);
      alpha[beg + lane] = pv;
      sm = pv;
    }
  } else {
    for (int p = beg + lane; p < end; p += 64) {
      float pv = __expf(alpha[p] - mx);
      alpha[p] = pv;
      sm += pv;
    }
  }
#pragma unroll
  for (int off = 32; off; off >>= 1) sm += __shfl_xor(sm, off);
  if (lane == 0) ssum[n] = sm;
}

__global__ void k_l2_agg(const int* __restrict__ row_ptr, const int* __restrict__ csr_src,
                         const float* __restrict__ h2, const float* __restrict__ alpha, const float* __restrict__ s2,
                         const float* __restrict__ sk2, const float* __restrict__ c2b, const float* __restrict__ s2b,
                         float* __restrict__ out, int N) {
  int n = blockIdx.x * TPB + threadIdx.x;
  if (n >= N) return;
  int beg = row_ptr[n], end = row_ptr[n + 1];
  float acc = 0.f;
  for (int p = beg; p < end; ++p) acc += alpha[p] * h2[csr_src[p]];
  float v = acc / (s2[n] + 1e-16f) + c2b[0] + sk2[n] + s2b[0];
  out[n] = 1.f / (1.f + __expf(-v));
}

// ---------------- host orchestration -----------------------------------------
extern "C" void kernel_launch(void* const* d_in, const int* in_sizes, int n_in,
                              void* d_out, int out_size, void* d_ws, size_t ws_size,
                              hipStream_t stream) {
  const float* x = (const float*)d_in[0];
  const int* ei = (const int*)d_in[1];
  const float* c0_w = (const float*)d_in[3];
  const float* c0_as = (const float*)d_in[4];
  const float* c0_ad = (const float*)d_in[5];
  const float* c0_b = (const float*)d_in[6];
  const float* s0_w = (const float*)d_in[7];
  const float* s0_b = (const float*)d_in[8];
  const float* c1_w = (const float*)d_in[9];
  const float* c1_as = (const float*)d_in[10];
  const float* c1_ad = (const float*)d_in[11];
  const float* c1_b = (const float*)d_in[12];
  const float* s1_w = (const float*)d_in[13];
  const float* s1_b = (const float*)d_in[14];
  const float* c2_w = (const float*)d_in[15];
  const float* c2_as = (const float*)d_in[16];
  const float* c2_ad = (const float*)d_in[17];
  const float* c2_b = (const float*)d_in[18];
  const float* s2_w = (const float*)d_in[19];
  const float* s2_b = (const float*)d_in[20];

  const int N = in_sizes[0] / 128;
  const int E = in_sizes[1] / 2;
  const int EN = E + N;
  const int* srcE = ei;
  const int* dstE = ei + E;

  // bump allocator over d_ws
  char* wp_ = (char*)d_ws;
  auto alloc = [&](size_t bytes) -> void* {
    void* r = (void*)wp_;
    wp_ += (bytes + 255) & ~(size_t)255;
    return r;
  };
  float* P0 = (float*)alloc((size_t)N * 128 * 4);  // H (lin out)
  float* P1 = (float*)alloc((size_t)N * 128 * 4);  // skip
  float* P2 = (float*)alloc((size_t)N * 128 * 4);  // layer outputs (in-place rotate)
  float* a_s = (float*)alloc((size_t)N * 4 * 4);
  float* a_d = (float*)alloc((size_t)N * 4 * 4);
  float* ssum = (float*)alloc((size_t)N * 4 * 4);
  float* alpha = (float*)alloc((size_t)EN * 4 * 4);  // CSR-ordered, unnormalized
  float* WB = (float*)alloc(128 * 256 * 4);
  int* deg = (int*)alloc((size_t)N * 4);
  int* row_ptr = (int*)alloc((size_t)(N + 1) * 4);
  int* cursor = (int*)alloc((size_t)N * 4);
  int* csum = (int*)alloc(4096 * 4);
  int* csr_src = (int*)alloc((size_t)EN * 4);
  float* h2 = (float*)alloc((size_t)N * 4);
  float* sk2 = (float*)alloc((size_t)N * 4);
  float* as2 = (float*)alloc((size_t)N * 4);
  float* ad2 = (float*)alloc((size_t)N * 4);

  const int gEN = (EN + TPB - 1) / TPB;
  const int gN4 = (N * 4 + TPB - 1) / TPB;
  const int gN = (N + TPB - 1) / TPB;
  const int nch = (N + TPB - 1) / TPB;
  const int gGemm = (N + 31) / 32;
  const int gWave = (N + 3) / 4;  // 4 waves/block, 1 node/wave

  // ---- CSR build (once per call; graph shared by all layers) ----
  hipMemsetAsync(deg, 0, (size_t)N * 4, stream);
  k_hist<<<gEN, TPB, 0, stream>>>(dstE, E, N, deg);
  k_scan1<<<nch, TPB, 0, stream>>>(deg, N, csum);
  k_scan2<<<1, TPB, 0, stream>>>(csum, nch);
  k_scan3<<<nch, TPB, 0, stream>>>(deg, csum, N, EN, row_ptr, cursor);
  k_scatter<<<gEN, TPB, 0, stream>>>(srcE, dstE, E, N, cursor, csr_src);

  // ---- layer 0 ----
  k_prep_w<<<128, TPB, 0, stream>>>(c0_w, s0_w, WB);
  k_gemm<<<gGemm, TPB, 0, stream>>>(x, WB, P0, P1, N);
  k_asad<<<gN4, TPB, 0, stream>>>(P0, c0_as, c0_ad, a_s, a_d, N);
  k_softmax4<<<gWave, TPB, 0, stream>>>(row_ptr, csr_src, (const float4*)a_s, (const float4*)a_d,
                                        (float4*)alpha, ssum, N);
  k_aggregate<<<(N + 1) / 2, TPB, 0, stream>>>(row_ptr, csr_src, P0, alpha, ssum, P1, c0_b, s0_b, P2, N);

  // ---- layer 1 (input P2, output overwrites P2) ----
  k_prep_w<<<128, TPB, 0, stream>>>(c1_w, s1_w, WB);
  k_gemm<<<gGemm, TPB, 0, stream>>>(P2, WB, P0, P1, N);
  k_asad<<<gN4, TPB, 0, stream>>>(P0, c1_as, c1_ad, a_s, a_d, N);
  k_softmax4<<<gWave, TPB, 0, stream>>>(row_ptr, csr_src, (const float4*)a_s, (const float4*)a_d,
                                        (float4*)alpha, ssum, N);
  k_aggregate<<<(N + 1) / 2, TPB, 0, stream>>>(row_ptr, csr_src, P0, alpha, ssum, P1, c1_b, s1_b, P2, N);

  // ---- layer 2 (H=1,C=1) ----
  k_l2_lin<<<(N * 64 + TPB - 1) / TPB, TPB, 0, stream>>>(P2, c2_w, s2_w, c2_as, c2_ad, h2, sk2, as2, ad2, N);
  k_l2_softmax<<<gWave, TPB, 0, stream>>>(row_ptr, csr_src, as2, ad2, alpha, ssum, N);
  k_l2_agg<<<gN, TPB, 0, stream>>>(row_ptr, csr_src, h2, alpha, ssum, sk2, c2_b, s2_b, (float*)d_out, N);
}

// Round 3
// 555.513 us; speedup vs baseline: 2.5860x; 1.4147x over previous
//
#include <hip/hip_runtime.h>
#include <math.h>

#define TPB 256

static __device__ __forceinline__ float lrelu(float x) { return x > 0.f ? x : 0.2f * x; }
// fp32 -> bf16 round-to-nearest-even
static __device__ __forceinline__ unsigned short f2bf(float f) {
  unsigned u = __float_as_uint(f);
  u += 0x7fffu + ((u >> 16) & 1u);
  return (unsigned short)(u >> 16);
}
static __device__ __forceinline__ float bflo(unsigned w) { return __uint_as_float(w << 16); }
static __device__ __forceinline__ float bfhi(unsigned w) { return __uint_as_float(w & 0xffff0000u); }

// ---------------- CSR build (graph is identical for all 3 layers) -------------
__global__ void k_hist(const int* __restrict__ dstE, int E, int N, int* __restrict__ deg) {
  int e = blockIdx.x * TPB + threadIdx.x;
  if (e >= E + N) return;
  int d = (e < E) ? dstE[e] : (e - E);
  d = min(max(d, 0), N - 1);
  atomicAdd(&deg[d], 1);
}

__global__ void k_scan1(const int* __restrict__ deg, int N, int* __restrict__ csum) {
  __shared__ int sm[TPB];
  int t = threadIdx.x, i = blockIdx.x * TPB + t;
  sm[t] = (i < N) ? deg[i] : 0;
  __syncthreads();
  for (int off = TPB / 2; off; off >>= 1) {
    if (t < off) sm[t] += sm[t + off];
    __syncthreads();
  }
  if (t == 0) csum[blockIdx.x] = sm[0];
}

__global__ void k_scan2(int* __restrict__ csum, int nch) {
  __shared__ int sm[TPB];
  int t = threadIdx.x;
  int v = (t < nch) ? csum[t] : 0;
  sm[t] = v;
  __syncthreads();
  for (int off = 1; off < TPB; off <<= 1) {
    int add = (t >= off) ? sm[t - off] : 0;
    __syncthreads();
    sm[t] += add;
    __syncthreads();
  }
  if (t < nch) csum[t] = (t == 0) ? 0 : sm[t - 1];  // exclusive chunk offsets
}

__global__ void k_scan3(const int* __restrict__ deg, const int* __restrict__ csum, int N, int total,
                        int* __restrict__ row_ptr, int* __restrict__ cursor) {
  __shared__ int sm[TPB];
  int b = blockIdx.x, t = threadIdx.x, i = b * TPB + t;
  int v = (i < N) ? deg[i] : 0;
  sm[t] = v;
  __syncthreads();
  for (int off = 1; off < TPB; off <<= 1) {
    int add = (t >= off) ? sm[t - off] : 0;
    __syncthreads();
    sm[t] += add;
    __syncthreads();
  }
  if (i < N) {
    int rp = csum[b] + sm[t] - v;  // exclusive
    row_ptr[i] = rp;
    cursor[i] = rp;
  }
  if (i == 0) row_ptr[N] = total;
}

__global__ void k_scatter(const int* __restrict__ srcE, const int* __restrict__ dstE, int E, int N,
                          int* __restrict__ cursor, int* __restrict__ csr_src) {
  int e = blockIdx.x * TPB + threadIdx.x;
  if (e >= E + N) return;
  int s = (e < E) ? srcE[e] : (e - E);
  int d = (e < E) ? dstE[e] : (e - E);
  s = min(max(s, 0), N - 1);
  d = min(max(d, 0), N - 1);
  int pos = atomicAdd(&cursor[d], 1);
  csr_src[pos] = s;
}

// ---------------- GEMM: H16 = bf16(X @ cW), S = X @ sW^T ----------------------
__global__ void k_prep_w(const float* __restrict__ cW, const float* __restrict__ sW, float* __restrict__ WB) {
  int k = blockIdx.x;   // 0..127
  int j = threadIdx.x;  // 0..255
  WB[k * 256 + j] = (j < 128) ? cW[k * 128 + j] : sW[(j - 128) * 128 + k];
}

__global__ __launch_bounds__(TPB) void k_gemm(const float* __restrict__ X, const float* __restrict__ WB,
                                              unsigned short* __restrict__ H16, float* __restrict__ Sb, int N) {
  __shared__ float Xs[32][128];
  int r0 = blockIdx.x * 32;
  int tid = threadIdx.x;
  int nrow = min(32, N - r0);
  const float4* Xv = (const float4*)(X + (size_t)r0 * 128);
  float4* Xsv = (float4*)(&Xs[0][0]);
  for (int i = tid; i < nrow * 32; i += TPB) Xsv[i] = Xv[i];
  __syncthreads();

  float acc[32];
#pragma unroll
  for (int r = 0; r < 32; ++r) acc[r] = 0.f;

  const float* wp = WB + tid;
#pragma unroll 1
  for (int k4 = 0; k4 < 32; ++k4) {
    float w0 = wp[(k4 * 4 + 0) * 256];
    float w1 = wp[(k4 * 4 + 1) * 256];
    float w2 = wp[(k4 * 4 + 2) * 256];
    float w3 = wp[(k4 * 4 + 3) * 256];
#pragma unroll
    for (int r = 0; r < 32; ++r) {
      float4 xv = *(const float4*)(&Xs[r][k4 * 4]);
      acc[r] = fmaf(xv.x, w0, acc[r]);
      acc[r] = fmaf(xv.y, w1, acc[r]);
      acc[r] = fmaf(xv.z, w2, acc[r]);
      acc[r] = fmaf(xv.w, w3, acc[r]);
    }
  }
  if (tid < 128) {
    unsigned short* outp = H16 + (size_t)r0 * 128 + tid;
    for (int r = 0; r < nrow; ++r) outp[(size_t)r * 128] = f2bf(acc[r]);
  } else {
    float* outp = Sb + (size_t)r0 * 128 + (tid - 128);
    for (int r = 0; r < nrow; ++r) outp[(size_t)r * 128] = acc[r];
  }
}

// ---------------- per-node attention coefficients a_s, a_d (bf16 H) ----------
__global__ void k_asad(const unsigned short* __restrict__ H16, const float* __restrict__ asrc,
                       const float* __restrict__ adst, float* __restrict__ a_s, float* __restrict__ a_d, int N) {
  int i = blockIdx.x * TPB + threadIdx.x;
  if (i >= N * 4) return;
  int n = i >> 2, h = i & 3;
  const uint4* hp = (const uint4*)(H16 + (size_t)n * 128 + h * 32);
  const float4* ap = (const float4*)(asrc + h * 32);
  const float4* bp = (const float4*)(adst + h * 32);
  float sa = 0.f, sd = 0.f;
#pragma unroll
  for (int q = 0; q < 4; ++q) {
    uint4 v = hp[q];
    float f0 = bflo(v.x), f1 = bfhi(v.x), f2 = bflo(v.y), f3 = bfhi(v.y);
    float f4 = bflo(v.z), f5 = bfhi(v.z), f6 = bflo(v.w), f7 = bfhi(v.w);
    float4 a0 = ap[q * 2], a1 = ap[q * 2 + 1];
    float4 b0 = bp[q * 2], b1 = bp[q * 2 + 1];
    sa += f0 * a0.x + f1 * a0.y + f2 * a0.z + f3 * a0.w + f4 * a1.x + f5 * a1.y + f6 * a1.z + f7 * a1.w;
    sd += f0 * b0.x + f1 * b0.y + f2 * b0.z + f3 * b0.w + f4 * b1.x + f5 * b1.y + f6 * b1.z + f7 * b1.w;
  }
  a_s[i] = sa;
  a_d[i] = sd;
}

// ---------------- fused softmax + aggregate, wave-per-node (H=4) --------------
// lane L owns channels (2L, 2L+1), head = L>>4. Alpha lives in registers for
// deg<=64 (the ~always case); rare big nodes take a spill-buffer slow path.
__global__ __launch_bounds__(TPB) void k_smax_agg(const int* __restrict__ row_ptr, const int* __restrict__ csr_src,
                                                  const float4* __restrict__ a_s4, const float4* __restrict__ a_d4,
                                                  const unsigned short* __restrict__ H16,
                                                  const float* __restrict__ Sk, const float* __restrict__ cb,
                                                  const float* __restrict__ sb, float4* __restrict__ spill,
                                                  float* __restrict__ Xn, int N) {
  int n = blockIdx.x * 4 + (threadIdx.x >> 6);
  if (n >= N) return;
  int lane = threadIdx.x & 63;
  int beg = row_ptr[n], end = row_ptr[n + 1];
  int deg = end - beg;
  float4 ad = a_d4[n];
  int h = lane >> 4;
  float acc0 = 0.f, acc1 = 0.f;

  if (deg <= 64) {
    int s_l = (lane < deg) ? csr_src[beg + lane] : 0;
    float4 lg = make_float4(-1e30f, -1e30f, -1e30f, -1e30f);
    if (lane < deg) {
      float4 as = a_s4[s_l];
      lg.x = lrelu(as.x + ad.x);
      lg.y = lrelu(as.y + ad.y);
      lg.z = lrelu(as.z + ad.z);
      lg.w = lrelu(as.w + ad.w);
    }
    float4 mx = lg;
#pragma unroll
    for (int off = 32; off; off >>= 1) {
      mx.x = fmaxf(mx.x, __shfl_xor(mx.x, off));
      mx.y = fmaxf(mx.y, __shfl_xor(mx.y, off));
      mx.z = fmaxf(mx.z, __shfl_xor(mx.z, off));
      mx.w = fmaxf(mx.w, __shfl_xor(mx.w, off));
    }
    float4 pv = make_float4(0.f, 0.f, 0.f, 0.f);
    if (lane < deg) {
      pv.x = __expf(lg.x - mx.x);
      pv.y = __expf(lg.y - mx.y);
      pv.z = __expf(lg.z - mx.z);
      pv.w = __expf(lg.w - mx.w);
    }
    float4 sm = pv;
#pragma unroll
    for (int off = 32; off; off >>= 1) {
      sm.x += __shfl_xor(sm.x, off);
      sm.y += __shfl_xor(sm.y, off);
      sm.z += __shfl_xor(sm.z, off);
      sm.w += __shfl_xor(sm.w, off);
    }
    pv.x *= 1.f / (sm.x + 1e-16f);
    pv.y *= 1.f / (sm.y + 1e-16f);
    pv.z *= 1.f / (sm.z + 1e-16f);
    pv.w *= 1.f / (sm.w + 1e-16f);
    for (int j = 0; j < deg; ++j) {
      int s = __shfl(s_l, j);
      float a0 = __shfl(pv.x, j), a1 = __shfl(pv.y, j), a2 = __shfl(pv.z, j), a3 = __shfl(pv.w, j);
      float av = (h == 0) ? a0 : (h == 1) ? a1 : (h == 2) ? a2 : a3;
      unsigned w = *(const unsigned*)(H16 + (size_t)s * 128 + lane * 2);
      acc0 = fmaf(av, bflo(w), acc0);
      acc1 = fmaf(av, bfhi(w), acc1);
    }
  } else {
    // slow path (deg>64): spill logits/weights to global
    float4 mx = make_float4(-1e30f, -1e30f, -1e30f, -1e30f);
    for (int p = beg + lane; p < end; p += 64) {
      int s = csr_src[p];
      float4 as = a_s4[s];
      float4 lg;
      lg.x = lrelu(as.x + ad.x);
      lg.y = lrelu(as.y + ad.y);
      lg.z = lrelu(as.z + ad.z);
      lg.w = lrelu(as.w + ad.w);
      spill[p] = lg;
      mx.x = fmaxf(mx.x, lg.x);
      mx.y = fmaxf(mx.y, lg.y);
      mx.z = fmaxf(mx.z, lg.z);
      mx.w = fmaxf(mx.w, lg.w);
    }
#pragma unroll
    for (int off = 32; off; off >>= 1) {
      mx.x = fmaxf(mx.x, __shfl_xor(mx.x, off));
      mx.y = fmaxf(mx.y, __shfl_xor(mx.y, off));
      mx.z = fmaxf(mx.z, __shfl_xor(mx.z, off));
      mx.w = fmaxf(mx.w, __shfl_xor(mx.w, off));
    }
    __threadfence_block();
    float4 sm = make_float4(0.f, 0.f, 0.f, 0.f);
    for (int p = beg + lane; p < end; p += 64) {
      float4 lg = spill[p];
      float4 pv;
      pv.x = __expf(lg.x - mx.x);
      pv.y = __expf(lg.y - mx.y);
      pv.z = __expf(lg.z - mx.z);
      pv.w = __expf(lg.w - mx.w);
      spill[p] = pv;
      sm.x += pv.x;
      sm.y += pv.y;
      sm.z += pv.z;
      sm.w += pv.w;
    }
#pragma unroll
    for (int off = 32; off; off >>= 1) {
      sm.x += __shfl_xor(sm.x, off);
      sm.y += __shfl_xor(sm.y, off);
      sm.z += __shfl_xor(sm.z, off);
      sm.w += __shfl_xor(sm.w, off);
    }
    float4 inv;
    inv.x = 1.f / (sm.x + 1e-16f);
    inv.y = 1.f / (sm.y + 1e-16f);
    inv.z = 1.f / (sm.z + 1e-16f);
    inv.w = 1.f / (sm.w + 1e-16f);
    __threadfence_block();
    for (int p = beg + lane; p < end; p += 64) {
      float4 pv = spill[p];
      pv.x *= inv.x;
      pv.y *= inv.y;
      pv.z *= inv.z;
      pv.w *= inv.w;
      spill[p] = pv;
    }
    __threadfence_block();
    const float* af = (const float*)spill;
    for (int p = beg; p < end; ++p) {
      int s = csr_src[p];
      float av = af[(size_t)p * 4 + h];
      unsigned w = *(const unsigned*)(H16 + (size_t)s * 128 + lane * 2);
      acc0 = fmaf(av, bflo(w), acc0);
      acc1 = fmaf(av, bfhi(w), acc1);
    }
  }

  int c = lane * 2;
  float2 sk = *(const float2*)(Sk + (size_t)n * 128 + c);
  float2 cbv = *(const float2*)(cb + c);
  float2 sbv = *(const float2*)(sb + c);
  float2 o;
  o.x = fmaxf(acc0 + cbv.x + sk.x + sbv.x, 0.f);
  o.y = fmaxf(acc1 + cbv.y + sk.y + sbv.y, 0.f);
  *(float2*)(Xn + (size_t)n * 128 + c) = o;
}

// ---------------- layer 2 (H=1, C=1) -----------------------------------------
__global__ void k_l2_lin(const float* __restrict__ X, const float* __restrict__ c2w, const float* __restrict__ s2w,
                         const float* __restrict__ c2as, const float* __restrict__ c2ad, float* __restrict__ h2,
                         float* __restrict__ sk2, float* __restrict__ as2, float* __restrict__ ad2, int N) {
  int gid = blockIdx.x * TPB + threadIdx.x;
  int n = gid >> 6;
  int lane = threadIdx.x & 63;
  if (n >= N) return;
  const float* xp = X + (size_t)n * 128;
  float2 xv = *(const float2*)(xp + lane * 2);
  float2 wv = *(const float2*)(c2w + lane * 2);
  float2 sv = *(const float2*)(s2w + lane * 2);
  float dh = xv.x * wv.x + xv.y * wv.y;
  float ds = xv.x * sv.x + xv.y * sv.y;
  for (int off = 32; off; off >>= 1) {
    dh += __shfl_down(dh, off);
    ds += __shfl_down(ds, off);
  }
  if (lane == 0) {
    h2[n] = dh;
    sk2[n] = ds;
    as2[n] = dh * c2as[0];
    ad2[n] = dh * c2ad[0];
  }
}

// fused softmax + aggregate (H=1, C=1), wave-per-node
__global__ __launch_bounds__(TPB) void k_l2_smax_agg(const int* __restrict__ row_ptr, const int* __restrict__ csr_src,
                                                     const float* __restrict__ as2, const float* __restrict__ ad2,
                                                     const float* __restrict__ h2, const float* __restrict__ sk2,
                                                     const float* __restrict__ c2b, const float* __restrict__ s2b,
                                                     float* __restrict__ out, int N) {
  int n = blockIdx.x * 4 + (threadIdx.x >> 6);
  if (n >= N) return;
  int lane = threadIdx.x & 63;
  int beg = row_ptr[n], end = row_ptr[n + 1];
  int deg = end - beg;
  float ad = ad2[n];
  float num = 0.f, den = 0.f;

  if (deg <= 64) {
    float lg = -1e30f, hv = 0.f;
    if (lane < deg) {
      int s = csr_src[beg + lane];
      lg = lrelu(as2[s] + ad);
      hv = h2[s];
    }
    float mx = lg;
#pragma unroll
    for (int off = 32; off; off >>= 1) mx = fmaxf(mx, __shfl_xor(mx, off));
    float pv = (lane < deg) ? __expf(lg - mx) : 0.f;
    num = pv * hv;
    den = pv;
  } else {
    float mx = -1e30f;
    for (int p = beg + lane; p < end; p += 64) mx = fmaxf(mx, lrelu(as2[csr_src[p]] + ad));
#pragma unroll
    for (int off = 32; off; off >>= 1) mx = fmaxf(mx, __shfl_xor(mx, off));
    for (int p = beg + lane; p < end; p += 64) {
      int s = csr_src[p];
      float pv = __expf(lrelu(as2[s] + ad) - mx);
      num += pv * h2[s];
      den += pv;
    }
  }
#pragma unroll
  for (int off = 32; off; off >>= 1) {
    num += __shfl_xor(num, off);
    den += __shfl_xor(den, off);
  }
  if (lane == 0) {
    float v = num / (den + 1e-16f) + c2b[0] + sk2[n] + s2b[0];
    out[n] = 1.f / (1.f + __expf(-v));
  }
}

// ---------------- host orchestration -----------------------------------------
extern "C" void kernel_launch(void* const* d_in, const int* in_sizes, int n_in,
                              void* d_out, int out_size, void* d_ws, size_t ws_size,
                              hipStream_t stream) {
  const float* x = (const float*)d_in[0];
  const int* ei = (const int*)d_in[1];
  const float* c0_w = (const float*)d_in[3];
  const float* c0_as = (const float*)d_in[4];
  const float* c0_ad = (const float*)d_in[5];
  const float* c0_b = (const float*)d_in[6];
  const float* s0_w = (const float*)d_in[7];
  const float* s0_b = (const float*)d_in[8];
  const float* c1_w = (const float*)d_in[9];
  const float* c1_as = (const float*)d_in[10];
  const float* c1_ad = (const float*)d_in[11];
  const float* c1_b = (const float*)d_in[12];
  const float* s1_w = (const float*)d_in[13];
  const float* s1_b = (const float*)d_in[14];
  const float* c2_w = (const float*)d_in[15];
  const float* c2_as = (const float*)d_in[16];
  const float* c2_ad = (const float*)d_in[17];
  const float* c2_b = (const float*)d_in[18];
  const float* s2_w = (const float*)d_in[19];
  const float* s2_b = (const float*)d_in[20];

  const int N = in_sizes[0] / 128;
  const int E = in_sizes[1] / 2;
  const int EN = E + N;
  const int* srcE = ei;
  const int* dstE = ei + E;

  // bump allocator over d_ws
  char* wp_ = (char*)d_ws;
  auto alloc = [&](size_t bytes) -> void* {
    void* r = (void*)wp_;
    wp_ += (bytes + 255) & ~(size_t)255;
    return r;
  };
  unsigned short* H16 = (unsigned short*)alloc((size_t)N * 128 * 2);  // bf16 lin out
  float* Sk = (float*)alloc((size_t)N * 128 * 4);                     // skip (fp32)
  float* P2 = (float*)alloc((size_t)N * 128 * 4);                     // layer io (fp32)
  float* a_s = (float*)alloc((size_t)N * 4 * 4);
  float* a_d = (float*)alloc((size_t)N * 4 * 4);
  float* spill = (float*)alloc((size_t)EN * 4 * 4);  // slow-path alpha spill
  float* WB = (float*)alloc(128 * 256 * 4);
  int* deg = (int*)alloc((size_t)N * 4);
  int* row_ptr = (int*)alloc((size_t)(N + 1) * 4);
  int* cursor = (int*)alloc((size_t)N * 4);
  int* csum = (int*)alloc(4096 * 4);
  int* csr_src = (int*)alloc((size_t)EN * 4);
  float* h2 = (float*)alloc((size_t)N * 4);
  float* sk2 = (float*)alloc((size_t)N * 4);
  float* as2 = (float*)alloc((size_t)N * 4);
  float* ad2 = (float*)alloc((size_t)N * 4);

  const int gEN = (EN + TPB - 1) / TPB;
  const int gN4 = (N * 4 + TPB - 1) / TPB;
  const int nch = (N + TPB - 1) / TPB;
  const int gGemm = (N + 31) / 32;
  const int gWave = (N + 3) / 4;  // 4 waves/block, 1 node/wave

  // ---- CSR build (once per call; graph shared by all layers) ----
  hipMemsetAsync(deg, 0, (size_t)N * 4, stream);
  k_hist<<<gEN, TPB, 0, stream>>>(dstE, E, N, deg);
  k_scan1<<<nch, TPB, 0, stream>>>(deg, N, csum);
  k_scan2<<<1, TPB, 0, stream>>>(csum, nch);
  k_scan3<<<nch, TPB, 0, stream>>>(deg, csum, N, EN, row_ptr, cursor);
  k_scatter<<<gEN, TPB, 0, stream>>>(srcE, dstE, E, N, cursor, csr_src);

  // ---- layer 0 ----
  k_prep_w<<<128, TPB, 0, stream>>>(c0_w, s0_w, WB);
  k_gemm<<<gGemm, TPB, 0, stream>>>(x, WB, H16, Sk, N);
  k_asad<<<gN4, TPB, 0, stream>>>(H16, c0_as, c0_ad, a_s, a_d, N);
  k_smax_agg<<<gWave, TPB, 0, stream>>>(row_ptr, csr_src, (const float4*)a_s, (const float4*)a_d, H16, Sk, c0_b,
                                        s0_b, (float4*)spill, P2, N);

  // ---- layer 1 (input P2, output overwrites P2) ----
  k_prep_w<<<128, TPB, 0, stream>>>(c1_w, s1_w, WB);
  k_gemm<<<gGemm, TPB, 0, stream>>>(P2, WB, H16, Sk, N);
  k_asad<<<gN4, TPB, 0, stream>>>(H16, c1_as, c1_ad, a_s, a_d, N);
  k_smax_agg<<<gWave, TPB, 0, stream>>>(row_ptr, csr_src, (const float4*)a_s, (const float4*)a_d, H16, Sk, c1_b,
                                        s1_b, (float4*)spill, P2, N);

  // ---- layer 2 (H=1,C=1) ----
  k_l2_lin<<<(N * 64 + TPB - 1) / TPB, TPB, 0, stream>>>(P2, c2_w, s2_w, c2_as, c2_ad, h2, sk2, as2, ad2, N);
  k_l2_smax_agg<<<gWave, TPB, 0, stream>>>(row_ptr, csr_src, as2, ad2, h2, sk2, c2_b, s2_b, (float*)d_out, N);
}

// Round 4
// 479.782 us; speedup vs baseline: 2.9942x; 1.1578x over previous
//
#include <hip/hip_runtime.h>
#include <math.h>

#define TPB 256

static __device__ __forceinline__ float lrelu(float x) { return x > 0.f ? x : 0.2f * x; }
// fp32 -> bf16 round-to-nearest-even
static __device__ __forceinline__ unsigned short f2bf(float f) {
  unsigned u = __float_as_uint(f);
  u += 0x7fffu + ((u >> 16) & 1u);
  return (unsigned short)(u >> 16);
}
static __device__ __forceinline__ float bflo(unsigned w) { return __uint_as_float(w << 16); }
static __device__ __forceinline__ float bfhi(unsigned w) { return __uint_as_float(w & 0xffff0000u); }

// ---------------- CSR build (graph is identical for all 3 layers) -------------
__global__ void k_hist(const int* __restrict__ dstE, int E, int N, int* __restrict__ deg) {
  int e = blockIdx.x * TPB + threadIdx.x;
  if (e >= E + N) return;
  int d = (e < E) ? dstE[e] : (e - E);
  d = min(max(d, 0), N - 1);
  atomicAdd(&deg[d], 1);
}

__global__ void k_scan1(const int* __restrict__ deg, int N, int* __restrict__ csum) {
  __shared__ int sm[TPB];
  int t = threadIdx.x, i = blockIdx.x * TPB + t;
  sm[t] = (i < N) ? deg[i] : 0;
  __syncthreads();
  for (int off = TPB / 2; off; off >>= 1) {
    if (t < off) sm[t] += sm[t + off];
    __syncthreads();
  }
  if (t == 0) csum[blockIdx.x] = sm[0];
}

__global__ void k_scan2(int* __restrict__ csum, int nch) {
  __shared__ int sm[TPB];
  int t = threadIdx.x;
  int v = (t < nch) ? csum[t] : 0;
  sm[t] = v;
  __syncthreads();
  for (int off = 1; off < TPB; off <<= 1) {
    int add = (t >= off) ? sm[t - off] : 0;
    __syncthreads();
    sm[t] += add;
    __syncthreads();
  }
  if (t < nch) csum[t] = (t == 0) ? 0 : sm[t - 1];  // exclusive chunk offsets
}

__global__ void k_scan3(const int* __restrict__ deg, const int* __restrict__ csum, int N, int total,
                        int* __restrict__ row_ptr, int* __restrict__ cursor) {
  __shared__ int sm[TPB];
  int b = blockIdx.x, t = threadIdx.x, i = b * TPB + t;
  int v = (i < N) ? deg[i] : 0;
  sm[t] = v;
  __syncthreads();
  for (int off = 1; off < TPB; off <<= 1) {
    int add = (t >= off) ? sm[t - off] : 0;
    __syncthreads();
    sm[t] += add;
    __syncthreads();
  }
  if (i < N) {
    int rp = csum[b] + sm[t] - v;  // exclusive
    row_ptr[i] = rp;
    cursor[i] = rp;
  }
  if (i == 0) row_ptr[N] = total;
}

__global__ void k_scatter(const int* __restrict__ srcE, const int* __restrict__ dstE, int E, int N,
                          int* __restrict__ cursor, int* __restrict__ csr_src) {
  int e = blockIdx.x * TPB + threadIdx.x;
  if (e >= E + N) return;
  int s = (e < E) ? srcE[e] : (e - E);
  int d = (e < E) ? dstE[e] : (e - E);
  s = min(max(s, 0), N - 1);
  d = min(max(d, 0), N - 1);
  int pos = atomicAdd(&cursor[d], 1);
  csr_src[pos] = s;
}

// ---------------- GEMM: H16 = bf16(X @ cW), S = X @ sW^T ----------------------
// WT layout: [col][k], col<128 -> cW column, col>=128 -> sW row (already [out][k])
__global__ void k_prep_w(const float* __restrict__ cW, const float* __restrict__ sW, float* __restrict__ WT) {
  int j = blockIdx.x;   // 0..255 output col
  int k = threadIdx.x;  // 0..127
  WT[j * 128 + k] = (j < 128) ? cW[k * 128 + j] : sW[(j - 128) * 128 + k];
}

// 64-row tile, 256 threads: thread owns cols (c, c+128) for 32 rows.
// 8 FMA per ds_read_b128 -> FMA-bound.
__global__ __launch_bounds__(TPB) void k_gemm(const float* __restrict__ X, const float* __restrict__ WT,
                                              unsigned short* __restrict__ H16, float* __restrict__ Sb, int N) {
  __shared__ float Xs[64][128];
  int r0 = blockIdx.x * 64;
  int tid = threadIdx.x;
  int nrow = min(64, N - r0);
  const float4* Xv = (const float4*)(X + (size_t)r0 * 128);
  float4* Xsv = (float4*)(&Xs[0][0]);
  int nv = nrow * 32;
  for (int i = tid; i < 64 * 32; i += TPB) Xsv[i] = (i < nv) ? Xv[i] : make_float4(0.f, 0.f, 0.f, 0.f);
  __syncthreads();

  int c = tid & 127;
  int rh = (tid >> 7) * 32;
  const float4* w0p = (const float4*)(WT + (size_t)c * 128);
  const float4* w1p = (const float4*)(WT + (size_t)(c + 128) * 128);

  float accH[32], accS[32];
#pragma unroll
  for (int r = 0; r < 32; ++r) {
    accH[r] = 0.f;
    accS[r] = 0.f;
  }

#pragma unroll 1
  for (int k4 = 0; k4 < 32; ++k4) {
    float4 w0 = w0p[k4];
    float4 w1 = w1p[k4];
#pragma unroll
    for (int r = 0; r < 32; ++r) {
      float4 xv = *(const float4*)(&Xs[rh + r][k4 * 4]);
      accH[r] = fmaf(xv.x, w0.x, accH[r]);
      accH[r] = fmaf(xv.y, w0.y, accH[r]);
      accH[r] = fmaf(xv.z, w0.z, accH[r]);
      accH[r] = fmaf(xv.w, w0.w, accH[r]);
      accS[r] = fmaf(xv.x, w1.x, accS[r]);
      accS[r] = fmaf(xv.y, w1.y, accS[r]);
      accS[r] = fmaf(xv.z, w1.z, accS[r]);
      accS[r] = fmaf(xv.w, w1.w, accS[r]);
    }
  }

  int nr = nrow - rh;
  nr = (nr < 0) ? 0 : ((nr > 32) ? 32 : nr);
  unsigned short* hp = H16 + (size_t)(r0 + rh) * 128 + c;
  float* sp = Sb + (size_t)(r0 + rh) * 128 + c;
  for (int r = 0; r < nr; ++r) {
    hp[(size_t)r * 128] = f2bf(accH[r]);
    sp[(size_t)r * 128] = accS[r];
  }
}

// ---------------- per-node attention coefficients a_s, a_d (bf16 H) ----------
__global__ void k_asad(const unsigned short* __restrict__ H16, const float* __restrict__ asrc,
                       const float* __restrict__ adst, float* __restrict__ a_s, float* __restrict__ a_d, int N) {
  int i = blockIdx.x * TPB + threadIdx.x;
  if (i >= N * 4) return;
  int n = i >> 2, h = i & 3;
  const uint4* hp = (const uint4*)(H16 + (size_t)n * 128 + h * 32);
  const float4* ap = (const float4*)(asrc + h * 32);
  const float4* bp = (const float4*)(adst + h * 32);
  float sa = 0.f, sd = 0.f;
#pragma unroll
  for (int q = 0; q < 4; ++q) {
    uint4 v = hp[q];
    float f0 = bflo(v.x), f1 = bfhi(v.x), f2 = bflo(v.y), f3 = bfhi(v.y);
    float f4 = bflo(v.z), f5 = bfhi(v.z), f6 = bflo(v.w), f7 = bfhi(v.w);
    float4 a0 = ap[q * 2], a1 = ap[q * 2 + 1];
    float4 b0 = bp[q * 2], b1 = bp[q * 2 + 1];
    sa += f0 * a0.x + f1 * a0.y + f2 * a0.z + f3 * a0.w + f4 * a1.x + f5 * a1.y + f6 * a1.z + f7 * a1.w;
    sd += f0 * b0.x + f1 * b0.y + f2 * b0.z + f3 * b0.w + f4 * b1.x + f5 * b1.y + f6 * b1.z + f7 * b1.w;
  }
  a_s[i] = sa;
  a_d[i] = sd;
}

// ---------------- fused softmax + aggregate, wave-per-node (H=4) --------------
// alpha + src staged in LDS (2 broadcast ds_reads/edge instead of 5 bpermutes),
// aggregation unrolled 4 edges/iter with zero-padded alpha (no guards).
__global__ __launch_bounds__(TPB) void k_smax_agg(const int* __restrict__ row_ptr, const int* __restrict__ csr_src,
                                                  const float4* __restrict__ a_s4, const float4* __restrict__ a_d4,
                                                  const unsigned short* __restrict__ H16,
                                                  const float* __restrict__ Sk, const float* __restrict__ cb,
                                                  const float* __restrict__ sb, float4* __restrict__ spill,
                                                  float* __restrict__ Xn, int N) {
  __shared__ int s_src[4][64];
  __shared__ float s_al[4][256];
  int wid = threadIdx.x >> 6;
  int n = blockIdx.x * 4 + wid;
  if (n >= N) return;
  int lane = threadIdx.x & 63;
  int beg = row_ptr[n], end = row_ptr[n + 1];
  int deg = end - beg;
  float4 ad = a_d4[n];
  int h = lane >> 4;
  float acc0 = 0.f, acc1 = 0.f;

  if (deg <= 64) {
    int s_l = 0;
    float4 lg = make_float4(-1e30f, -1e30f, -1e30f, -1e30f);
    if (lane < deg) {
      s_l = csr_src[beg + lane];
      float4 as = a_s4[s_l];
      lg.x = lrelu(as.x + ad.x);
      lg.y = lrelu(as.y + ad.y);
      lg.z = lrelu(as.z + ad.z);
      lg.w = lrelu(as.w + ad.w);
    }
    int maxoff = (deg <= 16) ? 8 : (deg <= 32) ? 16 : 32;  // wave-uniform
    float4 mx = lg;
    for (int off = 1; off <= maxoff; off <<= 1) {
      mx.x = fmaxf(mx.x, __shfl_xor(mx.x, off));
      mx.y = fmaxf(mx.y, __shfl_xor(mx.y, off));
      mx.z = fmaxf(mx.z, __shfl_xor(mx.z, off));
      mx.w = fmaxf(mx.w, __shfl_xor(mx.w, off));
    }
    float4 pv = make_float4(0.f, 0.f, 0.f, 0.f);
    if (lane < deg) {
      pv.x = __expf(lg.x - mx.x);
      pv.y = __expf(lg.y - mx.y);
      pv.z = __expf(lg.z - mx.z);
      pv.w = __expf(lg.w - mx.w);
    }
    float4 sm = pv;
    for (int off = 1; off <= maxoff; off <<= 1) {
      sm.x += __shfl_xor(sm.x, off);
      sm.y += __shfl_xor(sm.y, off);
      sm.z += __shfl_xor(sm.z, off);
      sm.w += __shfl_xor(sm.w, off);
    }
    pv.x *= 1.f / (sm.x + 1e-16f);
    pv.y *= 1.f / (sm.y + 1e-16f);
    pv.z *= 1.f / (sm.z + 1e-16f);
    pv.w *= 1.f / (sm.w + 1e-16f);
    s_src[wid][lane] = s_l;
    *(float4*)&s_al[wid][lane * 4] = pv;
    __builtin_amdgcn_wave_barrier();  // order LDS writes before reads (wave-synchronous)

    const unsigned short* Hb = H16 + lane * 2;
    int dpad = (deg + 3) & ~3;
    for (int j = 0; j < dpad; j += 4) {
      int s0 = s_src[wid][j + 0];
      int s1 = s_src[wid][j + 1];
      int s2 = s_src[wid][j + 2];
      int s3 = s_src[wid][j + 3];
      float a0 = s_al[wid][(j + 0) * 4 + h];
      float a1 = s_al[wid][(j + 1) * 4 + h];
      float a2 = s_al[wid][(j + 2) * 4 + h];
      float a3 = s_al[wid][(j + 3) * 4 + h];
      unsigned w0 = *(const unsigned*)(Hb + (size_t)s0 * 128);
      unsigned w1 = *(const unsigned*)(Hb + (size_t)s1 * 128);
      unsigned w2 = *(const unsigned*)(Hb + (size_t)s2 * 128);
      unsigned w3 = *(const unsigned*)(Hb + (size_t)s3 * 128);
      acc0 = fmaf(a0, bflo(w0), acc0);
      acc1 = fmaf(a0, bfhi(w0), acc1);
      acc0 = fmaf(a1, bflo(w1), acc0);
      acc1 = fmaf(a1, bfhi(w1), acc1);
      acc0 = fmaf(a2, bflo(w2), acc0);
      acc1 = fmaf(a2, bfhi(w2), acc1);
      acc0 = fmaf(a3, bflo(w3), acc0);
      acc1 = fmaf(a3, bfhi(w3), acc1);
    }
  } else {
    // slow path (deg>64): spill logits to global
    float4 mx = make_float4(-1e30f, -1e30f, -1e30f, -1e30f);
    for (int p = beg + lane; p < end; p += 64) {
      int s = csr_src[p];
      float4 as = a_s4[s];
      float4 lg;
      lg.x = lrelu(as.x + ad.x);
      lg.y = lrelu(as.y + ad.y);
      lg.z = lrelu(as.z + ad.z);
      lg.w = lrelu(as.w + ad.w);
      spill[p] = lg;
      mx.x = fmaxf(mx.x, lg.x);
      mx.y = fmaxf(mx.y, lg.y);
      mx.z = fmaxf(mx.z, lg.z);
      mx.w = fmaxf(mx.w, lg.w);
    }
#pragma unroll
    for (int off = 32; off; off >>= 1) {
      mx.x = fmaxf(mx.x, __shfl_xor(mx.x, off));
      mx.y = fmaxf(mx.y, __shfl_xor(mx.y, off));
      mx.z = fmaxf(mx.z, __shfl_xor(mx.z, off));
      mx.w = fmaxf(mx.w, __shfl_xor(mx.w, off));
    }
    __threadfence_block();
    float4 sm = make_float4(0.f, 0.f, 0.f, 0.f);
    for (int p = beg + lane; p < end; p += 64) {
      float4 lg = spill[p];
      float4 pv;
      pv.x = __expf(lg.x - mx.x);
      pv.y = __expf(lg.y - mx.y);
      pv.z = __expf(lg.z - mx.z);
      pv.w = __expf(lg.w - mx.w);
      spill[p] = pv;
      sm.x += pv.x;
      sm.y += pv.y;
      sm.z += pv.z;
      sm.w += pv.w;
    }
#pragma unroll
    for (int off = 32; off; off >>= 1) {
      sm.x += __shfl_xor(sm.x, off);
      sm.y += __shfl_xor(sm.y, off);
      sm.z += __shfl_xor(sm.z, off);
      sm.w += __shfl_xor(sm.w, off);
    }
    float4 inv;
    inv.x = 1.f / (sm.x + 1e-16f);
    inv.y = 1.f / (sm.y + 1e-16f);
    inv.z = 1.f / (sm.z + 1e-16f);
    inv.w = 1.f / (sm.w + 1e-16f);
    __threadfence_block();
    const float* af = (const float*)spill;
    for (int p = beg; p < end; ++p) {
      int s = csr_src[p];
      float av = af[(size_t)p * 4 + h] * ((h == 0) ? inv.x : (h == 1) ? inv.y : (h == 2) ? inv.z : inv.w);
      unsigned w = *(const unsigned*)(H16 + (size_t)s * 128 + lane * 2);
      acc0 = fmaf(av, bflo(w), acc0);
      acc1 = fmaf(av, bfhi(w), acc1);
    }
  }

  int c = lane * 2;
  float2 sk = *(const float2*)(Sk + (size_t)n * 128 + c);
  float2 cbv = *(const float2*)(cb + c);
  float2 sbv = *(const float2*)(sb + c);
  float2 o;
  o.x = fmaxf(acc0 + cbv.x + sk.x + sbv.x, 0.f);
  o.y = fmaxf(acc1 + cbv.y + sk.y + sbv.y, 0.f);
  *(float2*)(Xn + (size_t)n * 128 + c) = o;
}

// ---------------- layer 2 (H=1, C=1) -----------------------------------------
__global__ void k_l2_lin(const float* __restrict__ X, const float* __restrict__ c2w, const float* __restrict__ s2w,
                         const float* __restrict__ c2as, const float* __restrict__ c2ad, float* __restrict__ h2,
                         float* __restrict__ sk2, float* __restrict__ as2, float* __restrict__ ad2, int N) {
  int gid = blockIdx.x * TPB + threadIdx.x;
  int n = gid >> 6;
  int lane = threadIdx.x & 63;
  if (n >= N) return;
  const float* xp = X + (size_t)n * 128;
  float2 xv = *(const float2*)(xp + lane * 2);
  float2 wv = *(const float2*)(c2w + lane * 2);
  float2 sv = *(const float2*)(s2w + lane * 2);
  float dh = xv.x * wv.x + xv.y * wv.y;
  float ds = xv.x * sv.x + xv.y * sv.y;
  for (int off = 32; off; off >>= 1) {
    dh += __shfl_down(dh, off);
    ds += __shfl_down(ds, off);
  }
  if (lane == 0) {
    h2[n] = dh;
    sk2[n] = ds;
    as2[n] = dh * c2as[0];
    ad2[n] = dh * c2ad[0];
  }
}

// fused softmax + aggregate (H=1, C=1), wave-per-node
__global__ __launch_bounds__(TPB) void k_l2_smax_agg(const int* __restrict__ row_ptr, const int* __restrict__ csr_src,
                                                     const float* __restrict__ as2, const float* __restrict__ ad2,
                                                     const float* __restrict__ h2, const float* __restrict__ sk2,
                                                     const float* __restrict__ c2b, const float* __restrict__ s2b,
                                                     float* __restrict__ out, int N) {
  int n = blockIdx.x * 4 + (threadIdx.x >> 6);
  if (n >= N) return;
  int lane = threadIdx.x & 63;
  int beg = row_ptr[n], end = row_ptr[n + 1];
  int deg = end - beg;
  float ad = ad2[n];
  float num = 0.f, den = 0.f;

  if (deg <= 64) {
    float lg = -1e30f, hv = 0.f;
    if (lane < deg) {
      int s = csr_src[beg + lane];
      lg = lrelu(as2[s] + ad);
      hv = h2[s];
    }
    float mx = lg;
#pragma unroll
    for (int off = 32; off; off >>= 1) mx = fmaxf(mx, __shfl_xor(mx, off));
    float pv = (lane < deg) ? __expf(lg - mx) : 0.f;
    num = pv * hv;
    den = pv;
  } else {
    float mx = -1e30f;
    for (int p = beg + lane; p < end; p += 64) mx = fmaxf(mx, lrelu(as2[csr_src[p]] + ad));
#pragma unroll
    for (int off = 32; off; off >>= 1) mx = fmaxf(mx, __shfl_xor(mx, off));
    for (int p = beg + lane; p < end; p += 64) {
      int s = csr_src[p];
      float pv = __expf(lrelu(as2[s] + ad) - mx);
      num += pv * h2[s];
      den += pv;
    }
  }
#pragma unroll
  for (int off = 32; off; off >>= 1) {
    num += __shfl_xor(num, off);
    den += __shfl_xor(den, off);
  }
  if (lane == 0) {
    float v = num / (den + 1e-16f) + c2b[0] + sk2[n] + s2b[0];
    out[n] = 1.f / (1.f + __expf(-v));
  }
}

// ---------------- host orchestration -----------------------------------------
extern "C" void kernel_launch(void* const* d_in, const int* in_sizes, int n_in,
                              void* d_out, int out_size, void* d_ws, size_t ws_size,
                              hipStream_t stream) {
  const float* x = (const float*)d_in[0];
  const int* ei = (const int*)d_in[1];
  const float* c0_w = (const float*)d_in[3];
  const float* c0_as = (const float*)d_in[4];
  const float* c0_ad = (const float*)d_in[5];
  const float* c0_b = (const float*)d_in[6];
  const float* s0_w = (const float*)d_in[7];
  const float* s0_b = (const float*)d_in[8];
  const float* c1_w = (const float*)d_in[9];
  const float* c1_as = (const float*)d_in[10];
  const float* c1_ad = (const float*)d_in[11];
  const float* c1_b = (const float*)d_in[12];
  const float* s1_w = (const float*)d_in[13];
  const float* s1_b = (const float*)d_in[14];
  const float* c2_w = (const float*)d_in[15];
  const float* c2_as = (const float*)d_in[16];
  const float* c2_ad = (const float*)d_in[17];
  const float* c2_b = (const float*)d_in[18];
  const float* s2_w = (const float*)d_in[19];
  const float* s2_b = (const float*)d_in[20];

  const int N = in_sizes[0] / 128;
  const int E = in_sizes[1] / 2;
  const int EN = E + N;
  const int* srcE = ei;
  const int* dstE = ei + E;

  // bump allocator over d_ws
  char* wp_ = (char*)d_ws;
  auto alloc = [&](size_t bytes) -> void* {
    void* r = (void*)wp_;
    wp_ += (bytes + 255) & ~(size_t)255;
    return r;
  };
  unsigned short* H16 = (unsigned short*)alloc((size_t)N * 128 * 2);  // bf16 lin out
  float* Sk = (float*)alloc((size_t)N * 128 * 4);                     // skip (fp32)
  float* P2 = (float*)alloc((size_t)N * 128 * 4);                     // layer io (fp32)
  float* a_s = (float*)alloc((size_t)N * 4 * 4);
  float* a_d = (float*)alloc((size_t)N * 4 * 4);
  float* spill = (float*)alloc((size_t)EN * 4 * 4);  // slow-path alpha spill
  float* WT = (float*)alloc(256 * 128 * 4);
  int* deg = (int*)alloc((size_t)N * 4);
  int* row_ptr = (int*)alloc((size_t)(N + 1) * 4);
  int* cursor = (int*)alloc((size_t)N * 4);
  int* csum = (int*)alloc(4096 * 4);
  int* csr_src = (int*)alloc((size_t)EN * 4);
  float* h2 = (float*)alloc((size_t)N * 4);
  float* sk2 = (float*)alloc((size_t)N * 4);
  float* as2 = (float*)alloc((size_t)N * 4);
  float* ad2 = (float*)alloc((size_t)N * 4);

  const int gEN = (EN + TPB - 1) / TPB;
  const int gN4 = (N * 4 + TPB - 1) / TPB;
  const int nch = (N + TPB - 1) / TPB;
  const int gGemm = (N + 63) / 64;
  const int gWave = (N + 3) / 4;  // 4 waves/block, 1 node/wave

  // ---- CSR build (once per call; graph shared by all layers) ----
  hipMemsetAsync(deg, 0, (size_t)N * 4, stream);
  k_hist<<<gEN, TPB, 0, stream>>>(dstE, E, N, deg);
  k_scan1<<<nch, TPB, 0, stream>>>(deg, N, csum);
  k_scan2<<<1, TPB, 0, stream>>>(csum, nch);
  k_scan3<<<nch, TPB, 0, stream>>>(deg, csum, N, EN, row_ptr, cursor);
  k_scatter<<<gEN, TPB, 0, stream>>>(srcE, dstE, E, N, cursor, csr_src);

  // ---- layer 0 ----
  k_prep_w<<<256, 128, 0, stream>>>(c0_w, s0_w, WT);
  k_gemm<<<gGemm, TPB, 0, stream>>>(x, WT, H16, Sk, N);
  k_asad<<<gN4, TPB, 0, stream>>>(H16, c0_as, c0_ad, a_s, a_d, N);
  k_smax_agg<<<gWave, TPB, 0, stream>>>(row_ptr, csr_src, (const float4*)a_s, (const float4*)a_d, H16, Sk, c0_b,
                                        s0_b, (float4*)spill, P2, N);

  // ---- layer 1 (input P2, output overwrites P2) ----
  k_prep_w<<<256, 128, 0, stream>>>(c1_w, s1_w, WT);
  k_gemm<<<gGemm, TPB, 0, stream>>>(P2, WT, H16, Sk, N);
  k_asad<<<gN4, TPB, 0, stream>>>(H16, c1_as, c1_ad, a_s, a_d, N);
  k_smax_agg<<<gWave, TPB, 0, stream>>>(row_ptr, csr_src, (const float4*)a_s, (const float4*)a_d, H16, Sk, c1_b,
                                        s1_b, (float4*)spill, P2, N);

  // ---- layer 2 (H=1,C=1) ----
  k_l2_lin<<<(N * 64 + TPB - 1) / TPB, TPB, 0, stream>>>(P2, c2_w, s2_w, c2_as, c2_ad, h2, sk2, as2, ad2, N);
  k_l2_smax_agg<<<gWave, TPB, 0, stream>>>(row_ptr, csr_src, as2, ad2, h2, sk2, c2_b, s2_b, (float*)d_out, N);
}

// Round 5
// 388.366 us; speedup vs baseline: 3.6990x; 1.2354x over previous
//
#include <hip/hip_runtime.h>
#include <math.h>

#define TPB 256

typedef short bf16x8 __attribute__((ext_vector_type(8)));
typedef float f32x4 __attribute__((ext_vector_type(4)));

static __device__ __forceinline__ float lrelu(float x) { return x > 0.f ? x : 0.2f * x; }
// fp32 -> bf16 round-to-nearest-even
static __device__ __forceinline__ unsigned short f2bf(float f) {
  unsigned u = __float_as_uint(f);
  u += 0x7fffu + ((u >> 16) & 1u);
  return (unsigned short)(u >> 16);
}
static __device__ __forceinline__ float bflo(unsigned w) { return __uint_as_float(w << 16); }
static __device__ __forceinline__ float bfhi(unsigned w) { return __uint_as_float(w & 0xffff0000u); }

// ---------------- CSR build (graph is identical for all 3 layers) -------------
__global__ void k_hist(const int* __restrict__ dstE, int E, int N, int* __restrict__ deg) {
  int e = blockIdx.x * TPB + threadIdx.x;
  if (e >= E + N) return;
  int d = (e < E) ? dstE[e] : (e - E);
  d = min(max(d, 0), N - 1);
  atomicAdd(&deg[d], 1);
}

__global__ void k_scan1(const int* __restrict__ deg, int N, int* __restrict__ csum) {
  __shared__ int sm[TPB];
  int t = threadIdx.x, i = blockIdx.x * TPB + t;
  sm[t] = (i < N) ? deg[i] : 0;
  __syncthreads();
  for (int off = TPB / 2; off; off >>= 1) {
    if (t < off) sm[t] += sm[t + off];
    __syncthreads();
  }
  if (t == 0) csum[blockIdx.x] = sm[0];
}

__global__ void k_scan2(int* __restrict__ csum, int nch) {
  __shared__ int sm[TPB];
  int t = threadIdx.x;
  int v = (t < nch) ? csum[t] : 0;
  sm[t] = v;
  __syncthreads();
  for (int off = 1; off < TPB; off <<= 1) {
    int add = (t >= off) ? sm[t - off] : 0;
    __syncthreads();
    sm[t] += add;
    __syncthreads();
  }
  if (t < nch) csum[t] = (t == 0) ? 0 : sm[t - 1];  // exclusive chunk offsets
}

__global__ void k_scan3(const int* __restrict__ deg, const int* __restrict__ csum, int N, int total,
                        int* __restrict__ row_ptr, int* __restrict__ cursor) {
  __shared__ int sm[TPB];
  int b = blockIdx.x, t = threadIdx.x, i = b * TPB + t;
  int v = (i < N) ? deg[i] : 0;
  sm[t] = v;
  __syncthreads();
  for (int off = 1; off < TPB; off <<= 1) {
    int add = (t >= off) ? sm[t - off] : 0;
    __syncthreads();
    sm[t] += add;
    __syncthreads();
  }
  if (i < N) {
    int rp = csum[b] + sm[t] - v;  // exclusive
    row_ptr[i] = rp;
    cursor[i] = rp;
  }
  if (i == 0) row_ptr[N] = total;
}

__global__ void k_scatter(const int* __restrict__ srcE, const int* __restrict__ dstE, int E, int N,
                          int* __restrict__ cursor, int* __restrict__ csr_src) {
  int e = blockIdx.x * TPB + threadIdx.x;
  if (e >= E + N) return;
  int s = (e < E) ? srcE[e] : (e - E);
  int d = (e < E) ? dstE[e] : (e - E);
  s = min(max(s, 0), N - 1);
  d = min(max(d, 0), N - 1);
  int pos = atomicAdd(&cursor[d], 1);
  csr_src[pos] = s;
}

// ---------------- fp32 -> bf16 convert (8 elems/thread) -----------------------
__global__ void k_f2b(const float4* __restrict__ in, uint4* __restrict__ out, int n8) {
  int i = blockIdx.x * TPB + threadIdx.x;
  if (i >= n8) return;
  float4 v0 = in[i * 2], v1 = in[i * 2 + 1];
  uint4 o;
  o.x = (unsigned)f2bf(v0.x) | ((unsigned)f2bf(v0.y) << 16);
  o.y = (unsigned)f2bf(v0.z) | ((unsigned)f2bf(v0.w) << 16);
  o.z = (unsigned)f2bf(v1.x) | ((unsigned)f2bf(v1.y) << 16);
  o.w = (unsigned)f2bf(v1.z) | ((unsigned)f2bf(v1.w) << 16);
  out[i] = o;
}

// Wb[col][k] bf16: col<128 -> cW column, col>=128 -> sW row (B^T layout)
__global__ void k_prep_w(const float* __restrict__ cW, const float* __restrict__ sW,
                         unsigned short* __restrict__ Wb) {
  int j = blockIdx.x;   // 0..255 output col
  int k = threadIdx.x;  // 0..127
  Wb[j * 128 + k] = f2bf((j < 128) ? cW[k * 128 + j] : sW[(j - 128) * 128 + k]);
}

// ---------------- MFMA GEMM: [H16 | Sk] = Xb @ Wb^T (bf16 in, fp32 acc) -------
// Block: 64 rows x 256 cols, 4 waves (wave w -> cols 64w..64w+63). No LDS.
__global__ __launch_bounds__(TPB) void k_gemm_mfma(const unsigned short* __restrict__ Xb,
                                                   const unsigned short* __restrict__ Wb,
                                                   unsigned short* __restrict__ H16, float* __restrict__ Sb,
                                                   int NR) {
  int wid = threadIdx.x >> 6, lane = threadIdx.x & 63;
  int r0 = blockIdx.x * 64;
  int c0 = wid * 64;
  int l15 = lane & 15, lk = lane >> 4;

  f32x4 acc[4][4];
#pragma unroll
  for (int i = 0; i < 4; ++i)
#pragma unroll
    for (int j = 0; j < 4; ++j) acc[i][j] = (f32x4){0.f, 0.f, 0.f, 0.f};

#pragma unroll
  for (int ks = 0; ks < 4; ++ks) {
    bf16x8 a[4], b[4];
#pragma unroll
    for (int rt = 0; rt < 4; ++rt) {
      int row = min(r0 + rt * 16 + l15, NR - 1);
      a[rt] = *(const bf16x8*)(Xb + (size_t)row * 128 + ks * 32 + lk * 8);
    }
#pragma unroll
    for (int ct = 0; ct < 4; ++ct) {
      int col = c0 + ct * 16 + l15;
      b[ct] = *(const bf16x8*)(Wb + (size_t)col * 128 + ks * 32 + lk * 8);
    }
#pragma unroll
    for (int rt = 0; rt < 4; ++rt)
#pragma unroll
      for (int ct = 0; ct < 4; ++ct)
        acc[rt][ct] = __builtin_amdgcn_mfma_f32_16x16x32_bf16(a[rt], b[ct], acc[rt][ct], 0, 0, 0);
  }

  int orow = lk * 4;  // D: col = lane&15, row = (lane>>4)*4 + reg
#pragma unroll
  for (int rt = 0; rt < 4; ++rt) {
#pragma unroll
    for (int ct = 0; ct < 4; ++ct) {
      int col = c0 + ct * 16 + l15;
#pragma unroll
      for (int r = 0; r < 4; ++r) {
        int row = r0 + rt * 16 + orow + r;
        if (row < NR) {
          float v = acc[rt][ct][r];
          if (col < 128)
            H16[(size_t)row * 128 + col] = f2bf(v);
          else
            Sb[(size_t)row * 128 + (col - 128)] = v;
        }
      }
    }
  }
}

// ---------------- per-node attention coefficients a_s, a_d (bf16 H) ----------
__global__ void k_asad(const unsigned short* __restrict__ H16, const float* __restrict__ asrc,
                       const float* __restrict__ adst, float* __restrict__ a_s, float* __restrict__ a_d, int N) {
  int i = blockIdx.x * TPB + threadIdx.x;
  if (i >= N * 4) return;
  int n = i >> 2, h = i & 3;
  const uint4* hp = (const uint4*)(H16 + (size_t)n * 128 + h * 32);
  const float4* ap = (const float4*)(asrc + h * 32);
  const float4* bp = (const float4*)(adst + h * 32);
  float sa = 0.f, sd = 0.f;
#pragma unroll
  for (int q = 0; q < 4; ++q) {
    uint4 v = hp[q];
    float f0 = bflo(v.x), f1 = bfhi(v.x), f2 = bflo(v.y), f3 = bfhi(v.y);
    float f4 = bflo(v.z), f5 = bfhi(v.z), f6 = bflo(v.w), f7 = bfhi(v.w);
    float4 a0 = ap[q * 2], a1 = ap[q * 2 + 1];
    float4 b0 = bp[q * 2], b1 = bp[q * 2 + 1];
    sa += f0 * a0.x + f1 * a0.y + f2 * a0.z + f3 * a0.w + f4 * a1.x + f5 * a1.y + f6 * a1.z + f7 * a1.w;
    sd += f0 * b0.x + f1 * b0.y + f2 * b0.z + f3 * b0.w + f4 * b1.x + f5 * b1.y + f6 * b1.z + f7 * b1.w;
  }
  a_s[i] = sa;
  a_d[i] = sd;
}

// ---------------- fused softmax + aggregate, wave-per-node (H=4) --------------
// BF=true: write bf16 (feeds next MFMA GEMM); BF=false: write fp32.
template <bool BF>
__global__ __launch_bounds__(TPB) void k_smax_agg(const int* __restrict__ row_ptr, const int* __restrict__ csr_src,
                                                  const float4* __restrict__ a_s4, const float4* __restrict__ a_d4,
                                                  const unsigned short* __restrict__ H16,
                                                  const float* __restrict__ Sk, const float* __restrict__ cb,
                                                  const float* __restrict__ sb, float4* __restrict__ spill,
                                                  float* __restrict__ XnF, unsigned short* __restrict__ XnB,
                                                  int N) {
  __shared__ int s_src[4][64];
  __shared__ float s_al[4][256];
  int wid = threadIdx.x >> 6;
  int n = blockIdx.x * 4 + wid;
  if (n >= N) return;
  int lane = threadIdx.x & 63;
  int beg = row_ptr[n], end = row_ptr[n + 1];
  int deg = end - beg;
  float4 ad = a_d4[n];
  int h = lane >> 4;
  float acc0 = 0.f, acc1 = 0.f;

  if (deg <= 64) {
    int s_l = 0;
    float4 lg = make_float4(-1e30f, -1e30f, -1e30f, -1e30f);
    if (lane < deg) {
      s_l = csr_src[beg + lane];
      float4 as = a_s4[s_l];
      lg.x = lrelu(as.x + ad.x);
      lg.y = lrelu(as.y + ad.y);
      lg.z = lrelu(as.z + ad.z);
      lg.w = lrelu(as.w + ad.w);
    }
    int maxoff = (deg <= 16) ? 8 : (deg <= 32) ? 16 : 32;  // wave-uniform
    float4 mx = lg;
    for (int off = 1; off <= maxoff; off <<= 1) {
      mx.x = fmaxf(mx.x, __shfl_xor(mx.x, off));
      mx.y = fmaxf(mx.y, __shfl_xor(mx.y, off));
      mx.z = fmaxf(mx.z, __shfl_xor(mx.z, off));
      mx.w = fmaxf(mx.w, __shfl_xor(mx.w, off));
    }
    float4 pv = make_float4(0.f, 0.f, 0.f, 0.f);
    if (lane < deg) {
      pv.x = __expf(lg.x - mx.x);
      pv.y = __expf(lg.y - mx.y);
      pv.z = __expf(lg.z - mx.z);
      pv.w = __expf(lg.w - mx.w);
    }
    float4 sm = pv;
    for (int off = 1; off <= maxoff; off <<= 1) {
      sm.x += __shfl_xor(sm.x, off);
      sm.y += __shfl_xor(sm.y, off);
      sm.z += __shfl_xor(sm.z, off);
      sm.w += __shfl_xor(sm.w, off);
    }
    pv.x *= 1.f / (sm.x + 1e-16f);
    pv.y *= 1.f / (sm.y + 1e-16f);
    pv.z *= 1.f / (sm.z + 1e-16f);
    pv.w *= 1.f / (sm.w + 1e-16f);
    s_src[wid][lane] = s_l;
    *(float4*)&s_al[wid][lane * 4] = pv;
    __builtin_amdgcn_wave_barrier();  // order LDS writes before reads (wave-synchronous)

    const unsigned short* Hb = H16 + lane * 2;
    int dpad = (deg + 3) & ~3;
    for (int j = 0; j < dpad; j += 4) {
      int s0 = s_src[wid][j + 0];
      int s1 = s_src[wid][j + 1];
      int s2 = s_src[wid][j + 2];
      int s3 = s_src[wid][j + 3];
      float a0 = s_al[wid][(j + 0) * 4 + h];
      float a1 = s_al[wid][(j + 1) * 4 + h];
      float a2 = s_al[wid][(j + 2) * 4 + h];
      float a3 = s_al[wid][(j + 3) * 4 + h];
      unsigned w0 = *(const unsigned*)(Hb + (size_t)s0 * 128);
      unsigned w1 = *(const unsigned*)(Hb + (size_t)s1 * 128);
      unsigned w2 = *(const unsigned*)(Hb + (size_t)s2 * 128);
      unsigned w3 = *(const unsigned*)(Hb + (size_t)s3 * 128);
      acc0 = fmaf(a0, bflo(w0), acc0);
      acc1 = fmaf(a0, bfhi(w0), acc1);
      acc0 = fmaf(a1, bflo(w1), acc0);
      acc1 = fmaf(a1, bfhi(w1), acc1);
      acc0 = fmaf(a2, bflo(w2), acc0);
      acc1 = fmaf(a2, bfhi(w2), acc1);
      acc0 = fmaf(a3, bflo(w3), acc0);
      acc1 = fmaf(a3, bfhi(w3), acc1);
    }
  } else {
    // slow path (deg>64): spill logits to global
    float4 mx = make_float4(-1e30f, -1e30f, -1e30f, -1e30f);
    for (int p = beg + lane; p < end; p += 64) {
      int s = csr_src[p];
      float4 as = a_s4[s];
      float4 lg;
      lg.x = lrelu(as.x + ad.x);
      lg.y = lrelu(as.y + ad.y);
      lg.z = lrelu(as.z + ad.z);
      lg.w = lrelu(as.w + ad.w);
      spill[p] = lg;
      mx.x = fmaxf(mx.x, lg.x);
      mx.y = fmaxf(mx.y, lg.y);
      mx.z = fmaxf(mx.z, lg.z);
      mx.w = fmaxf(mx.w, lg.w);
    }
#pragma unroll
    for (int off = 32; off; off >>= 1) {
      mx.x = fmaxf(mx.x, __shfl_xor(mx.x, off));
      mx.y = fmaxf(mx.y, __shfl_xor(mx.y, off));
      mx.z = fmaxf(mx.z, __shfl_xor(mx.z, off));
      mx.w = fmaxf(mx.w, __shfl_xor(mx.w, off));
    }
    __threadfence_block();
    float4 sm = make_float4(0.f, 0.f, 0.f, 0.f);
    for (int p = beg + lane; p < end; p += 64) {
      float4 lg = spill[p];
      float4 pv;
      pv.x = __expf(lg.x - mx.x);
      pv.y = __expf(lg.y - mx.y);
      pv.z = __expf(lg.z - mx.z);
      pv.w = __expf(lg.w - mx.w);
      spill[p] = pv;
      sm.x += pv.x;
      sm.y += pv.y;
      sm.z += pv.z;
      sm.w += pv.w;
    }
#pragma unroll
    for (int off = 32; off; off >>= 1) {
      sm.x += __shfl_xor(sm.x, off);
      sm.y += __shfl_xor(sm.y, off);
      sm.z += __shfl_xor(sm.z, off);
      sm.w += __shfl_xor(sm.w, off);
    }
    float4 inv;
    inv.x = 1.f / (sm.x + 1e-16f);
    inv.y = 1.f / (sm.y + 1e-16f);
    inv.z = 1.f / (sm.z + 1e-16f);
    inv.w = 1.f / (sm.w + 1e-16f);
    __threadfence_block();
    const float* af = (const float*)spill;
    for (int p = beg; p < end; ++p) {
      int s = csr_src[p];
      float av = af[(size_t)p * 4 + h] * ((h == 0) ? inv.x : (h == 1) ? inv.y : (h == 2) ? inv.z : inv.w);
      unsigned w = *(const unsigned*)(H16 + (size_t)s * 128 + lane * 2);
      acc0 = fmaf(av, bflo(w), acc0);
      acc1 = fmaf(av, bfhi(w), acc1);
    }
  }

  int c = lane * 2;
  float2 sk = *(const float2*)(Sk + (size_t)n * 128 + c);
  float2 cbv = *(const float2*)(cb + c);
  float2 sbv = *(const float2*)(sb + c);
  float ox = fmaxf(acc0 + cbv.x + sk.x + sbv.x, 0.f);
  float oy = fmaxf(acc1 + cbv.y + sk.y + sbv.y, 0.f);
  if (BF) {
    unsigned pk = (unsigned)f2bf(ox) | ((unsigned)f2bf(oy) << 16);
    *(unsigned*)(XnB + (size_t)n * 128 + c) = pk;
  } else {
    *(float2*)(XnF + (size_t)n * 128 + c) = make_float2(ox, oy);
  }
}

// ---------------- layer 2 (H=1, C=1) -----------------------------------------
__global__ void k_l2_lin(const float* __restrict__ X, const float* __restrict__ c2w, const float* __restrict__ s2w,
                         const float* __restrict__ c2as, const float* __restrict__ c2ad, float* __restrict__ h2,
                         float* __restrict__ sk2, float* __restrict__ as2, float* __restrict__ ad2, int N) {
  int gid = blockIdx.x * TPB + threadIdx.x;
  int n = gid >> 6;
  int lane = threadIdx.x & 63;
  if (n >= N) return;
  const float* xp = X + (size_t)n * 128;
  float2 xv = *(const float2*)(xp + lane * 2);
  float2 wv = *(const float2*)(c2w + lane * 2);
  float2 sv = *(const float2*)(s2w + lane * 2);
  float dh = xv.x * wv.x + xv.y * wv.y;
  float ds = xv.x * sv.x + xv.y * sv.y;
  for (int off = 32; off; off >>= 1) {
    dh += __shfl_down(dh, off);
    ds += __shfl_down(ds, off);
  }
  if (lane == 0) {
    h2[n] = dh;
    sk2[n] = ds;
    as2[n] = dh * c2as[0];
    ad2[n] = dh * c2ad[0];
  }
}

// fused softmax + aggregate (H=1, C=1), wave-per-node
__global__ __launch_bounds__(TPB) void k_l2_smax_agg(const int* __restrict__ row_ptr, const int* __restrict__ csr_src,
                                                     const float* __restrict__ as2, const float* __restrict__ ad2,
                                                     const float* __restrict__ h2, const float* __restrict__ sk2,
                                                     const float* __restrict__ c2b, const float* __restrict__ s2b,
                                                     float* __restrict__ out, int N) {
  int n = blockIdx.x * 4 + (threadIdx.x >> 6);
  if (n >= N) return;
  int lane = threadIdx.x & 63;
  int beg = row_ptr[n], end = row_ptr[n + 1];
  int deg = end - beg;
  float ad = ad2[n];
  float num = 0.f, den = 0.f;

  if (deg <= 64) {
    float lg = -1e30f, hv = 0.f;
    if (lane < deg) {
      int s = csr_src[beg + lane];
      lg = lrelu(as2[s] + ad);
      hv = h2[s];
    }
    float mx = lg;
#pragma unroll
    for (int off = 32; off; off >>= 1) mx = fmaxf(mx, __shfl_xor(mx, off));
    float pv = (lane < deg) ? __expf(lg - mx) : 0.f;
    num = pv * hv;
    den = pv;
  } else {
    float mx = -1e30f;
    for (int p = beg + lane; p < end; p += 64) mx = fmaxf(mx, lrelu(as2[csr_src[p]] + ad));
#pragma unroll
    for (int off = 32; off; off >>= 1) mx = fmaxf(mx, __shfl_xor(mx, off));
    for (int p = beg + lane; p < end; p += 64) {
      int s = csr_src[p];
      float pv = __expf(lrelu(as2[s] + ad) - mx);
      num += pv * h2[s];
      den += pv;
    }
  }
#pragma unroll
  for (int off = 32; off; off >>= 1) {
    num += __shfl_xor(num, off);
    den += __shfl_xor(den, off);
  }
  if (lane == 0) {
    float v = num / (den + 1e-16f) + c2b[0] + sk2[n] + s2b[0];
    out[n] = 1.f / (1.f + __expf(-v));
  }
}

// ---------------- host orchestration -----------------------------------------
extern "C" void kernel_launch(void* const* d_in, const int* in_sizes, int n_in,
                              void* d_out, int out_size, void* d_ws, size_t ws_size,
                              hipStream_t stream) {
  const float* x = (const float*)d_in[0];
  const int* ei = (const int*)d_in[1];
  const float* c0_w = (const float*)d_in[3];
  const float* c0_as = (const float*)d_in[4];
  const float* c0_ad = (const float*)d_in[5];
  const float* c0_b = (const float*)d_in[6];
  const float* s0_w = (const float*)d_in[7];
  const float* s0_b = (const float*)d_in[8];
  const float* c1_w = (const float*)d_in[9];
  const float* c1_as = (const float*)d_in[10];
  const float* c1_ad = (const float*)d_in[11];
  const float* c1_b = (const float*)d_in[12];
  const float* s1_w = (const float*)d_in[13];
  const float* s1_b = (const float*)d_in[14];
  const float* c2_w = (const float*)d_in[15];
  const float* c2_as = (const float*)d_in[16];
  const float* c2_ad = (const float*)d_in[17];
  const float* c2_b = (const float*)d_in[18];
  const float* s2_w = (const float*)d_in[19];
  const float* s2_b = (const float*)d_in[20];

  const int N = in_sizes[0] / 128;
  const int E = in_sizes[1] / 2;
  const int EN = E + N;
  const int* srcE = ei;
  const int* dstE = ei + E;

  // bump allocator over d_ws
  char* wp_ = (char*)d_ws;
  auto alloc = [&](size_t bytes) -> void* {
    void* r = (void*)wp_;
    wp_ += (bytes + 255) & ~(size_t)255;
    return r;
  };
  unsigned short* Xb0 = (unsigned short*)alloc((size_t)N * 128 * 2);  // bf16 layer-0 input
  unsigned short* Xb1 = (unsigned short*)alloc((size_t)N * 128 * 2);  // bf16 layer-1 input
  unsigned short* H16 = (unsigned short*)alloc((size_t)N * 128 * 2);  // bf16 lin out
  float* Sk = (float*)alloc((size_t)N * 128 * 4);                     // skip (fp32)
  float* P2 = (float*)alloc((size_t)N * 128 * 4);                     // layer-1 out (fp32)
  float* a_s = (float*)alloc((size_t)N * 4 * 4);
  float* a_d = (float*)alloc((size_t)N * 4 * 4);
  float* spill = (float*)alloc((size_t)EN * 4 * 4);  // slow-path alpha spill
  unsigned short* Wb = (unsigned short*)alloc(256 * 128 * 2);
  int* deg = (int*)alloc((size_t)N * 4);
  int* row_ptr = (int*)alloc((size_t)(N + 1) * 4);
  int* cursor = (int*)alloc((size_t)N * 4);
  int* csum = (int*)alloc(4096 * 4);
  int* csr_src = (int*)alloc((size_t)EN * 4);
  float* h2 = (float*)alloc((size_t)N * 4);
  float* sk2 = (float*)alloc((size_t)N * 4);
  float* as2 = (float*)alloc((size_t)N * 4);
  float* ad2 = (float*)alloc((size_t)N * 4);

  const int gEN = (EN + TPB - 1) / TPB;
  const int gN4 = (N * 4 + TPB - 1) / TPB;
  const int nch = (N + TPB - 1) / TPB;
  const int gGemm = (N + 63) / 64;
  const int gWave = (N + 3) / 4;  // 4 waves/block, 1 node/wave
  const int n8 = N * 128 / 8;

  // ---- CSR build (once per call; graph shared by all layers) ----
  hipMemsetAsync(deg, 0, (size_t)N * 4, stream);
  k_hist<<<gEN, TPB, 0, stream>>>(dstE, E, N, deg);
  k_scan1<<<nch, TPB, 0, stream>>>(deg, N, csum);
  k_scan2<<<1, TPB, 0, stream>>>(csum, nch);
  k_scan3<<<nch, TPB, 0, stream>>>(deg, csum, N, EN, row_ptr, cursor);
  k_scatter<<<gEN, TPB, 0, stream>>>(srcE, dstE, E, N, cursor, csr_src);

  // ---- layer 0 ----
  k_f2b<<<(n8 + TPB - 1) / TPB, TPB, 0, stream>>>((const float4*)x, (uint4*)Xb0, n8);
  k_prep_w<<<256, 128, 0, stream>>>(c0_w, s0_w, Wb);
  k_gemm_mfma<<<gGemm, TPB, 0, stream>>>(Xb0, Wb, H16, Sk, N);
  k_asad<<<gN4, TPB, 0, stream>>>(H16, c0_as, c0_ad, a_s, a_d, N);
  k_smax_agg<true><<<gWave, TPB, 0, stream>>>(row_ptr, csr_src, (const float4*)a_s, (const float4*)a_d, H16, Sk,
                                              c0_b, s0_b, (float4*)spill, nullptr, Xb1, N);

  // ---- layer 1 ----
  k_prep_w<<<256, 128, 0, stream>>>(c1_w, s1_w, Wb);
  k_gemm_mfma<<<gGemm, TPB, 0, stream>>>(Xb1, Wb, H16, Sk, N);
  k_asad<<<gN4, TPB, 0, stream>>>(H16, c1_as, c1_ad, a_s, a_d, N);
  k_smax_agg<false><<<gWave, TPB, 0, stream>>>(row_ptr, csr_src, (const float4*)a_s, (const float4*)a_d, H16, Sk,
                                               c1_b, s1_b, (float4*)spill, P2, nullptr, N);

  // ---- layer 2 (H=1,C=1) ----
  k_l2_lin<<<(N * 64 + TPB - 1) / TPB, TPB, 0, stream>>>(P2, c2_w, s2_w, c2_as, c2_ad, h2, sk2, as2, ad2, N);
  k_l2_smax_agg<<<gWave, TPB, 0, stream>>>(row_ptr, csr_src, as2, ad2, h2, sk2, c2_b, s2_b, (float*)d_out, N);
}